// Round 6
// baseline (28883.163 us; speedup 1.0000x reference)
//
#include <hip/hip_runtime.h>
#include <math.h>

#define B_ 32
#define N_ 1023
#define E_ 256
#define H_ 512
#define V_ 32000
#define T_ 64
#define NBL 500   // logits col-tiles (64 cols each)
#define DECB 512  // persistent decoder blocks (2 per CU)

__device__ __forceinline__ float sigf(float x) { return 1.0f / (1.0f + expf(-x)); }

// ---------------------------------------------------------------------------
// grid barrier: one-shot counter per barrier instance (memset to 0 each call)
// ---------------------------------------------------------------------------
__device__ __forceinline__ void gridbar(unsigned* c)
{
    __syncthreads();
    if (threadIdx.x == 0) {
        __threadfence();
        __hip_atomic_fetch_add(c, 1u, __ATOMIC_ACQ_REL, __HIP_MEMORY_SCOPE_AGENT);
        while (__hip_atomic_load(c, __ATOMIC_ACQUIRE, __HIP_MEMORY_SCOPE_AGENT) < (unsigned)DECB) {
            __builtin_amdgcn_s_sleep(2);
        }
        __threadfence();
    }
    __syncthreads();
}

// ---------------------------------------------------------------------------
// Tree iou GEMM (large levels): 128x128 tile, 8x8 micro.
// ---------------------------------------------------------------------------
template<bool LEAF>
__global__ void __launch_bounds__(256)
iou_gemm_k(const int* __restrict__ node_feat, const int* __restrict__ mask,
           const float* __restrict__ emb, const float* __restrict__ Wiou,
           const float* __restrict__ Uiou, const float* __restrict__ hbuf,
           float* __restrict__ iou_out, int first, int n, int nshift)
{
    const int rows = B_ * n;
    const int K = LEAF ? E_ : (E_ + H_);
    const int rt = blockIdx.x, ct = blockIdx.y;
    const int tid = threadIdx.x;
    const int tr = tid >> 4, tc = tid & 15;

    __shared__ __align__(16) float As[8][136];
    __shared__ __align__(16) float Bs[8][136];

    float acc[8][8];
#pragma unroll
    for (int i = 0; i < 8; ++i)
#pragma unroll
        for (int j = 0; j < 8; ++j) acc[i][j] = 0.0f;

    const int lrow = tid >> 1;
    const int lkq  = (tid & 1) << 2;
    const int grow = rt * 128 + lrow;
    const bool rvalid = grow < rows;
    int tok = 0; float mval = 0.0f; int hoff1 = 0, hoff2 = 0;
    if (rvalid) {
        const int b = grow >> nshift, j = grow & (n - 1);
        const int node = first + j;
        tok  = node_feat[b * N_ + node];
        mval = (float)mask[b * N_ + node];
        if (!LEAF) {
            hoff1 = (b * N_ + 2 * node + 1) * H_;
            hoff2 = hoff1 + H_;
        }
    }
    const int bk   = tid >> 5;
    const int bcol = (tid & 31) << 2;
    const int gcol = ct * 128 + bcol;

    const int nkt = K >> 3;
    for (int kt = 0; kt < nkt; ++kt) {
        const int k0 = kt << 3;
        {
            const int kg = k0 + lkq;
            float4 v = make_float4(0.f, 0.f, 0.f, 0.f);
            if (rvalid) {
                if (LEAF || kg < E_) {
                    float4 e = *(const float4*)(emb + tok * E_ + kg);
                    v.x = e.x * mval; v.y = e.y * mval; v.z = e.z * mval; v.w = e.w * mval;
                } else {
                    const int kk = kg - E_;
                    float4 h1 = *(const float4*)(hbuf + hoff1 + kk);
                    float4 h2 = *(const float4*)(hbuf + hoff2 + kk);
                    v.x = h1.x + h2.x; v.y = h1.y + h2.y;
                    v.z = h1.z + h2.z; v.w = h1.w + h2.w;
                }
            }
            As[lkq + 0][lrow] = v.x;
            As[lkq + 1][lrow] = v.y;
            As[lkq + 2][lrow] = v.z;
            As[lkq + 3][lrow] = v.w;
        }
        {
            const int kg = k0 + bk;
            const float* src = (LEAF || kg < E_) ? (Wiou + kg * 1536 + gcol)
                                                 : (Uiou + (kg - E_) * 1536 + gcol);
            *(float4*)&Bs[bk][bcol] = *(const float4*)src;
        }
        __syncthreads();
#pragma unroll
        for (int kk = 0; kk < 8; ++kk) {
            float a[8], bb[8];
            *(float4*)&a[0]  = *(const float4*)&As[kk][tr << 3];
            *(float4*)&a[4]  = *(const float4*)&As[kk][(tr << 3) + 4];
            *(float4*)&bb[0] = *(const float4*)&Bs[kk][tc << 2];
            *(float4*)&bb[4] = *(const float4*)&Bs[kk][(tc << 2) + 64];
#pragma unroll
            for (int i = 0; i < 8; ++i)
#pragma unroll
                for (int j = 0; j < 8; ++j)
                    acc[i][j] = fmaf(a[i], bb[j], acc[i][j]);
        }
        __syncthreads();
    }
#pragma unroll
    for (int i = 0; i < 8; ++i) {
        const int r = rt * 128 + (tr << 3) + i;
        if (r < rows) {
            float* dst = iou_out + (size_t)r * 1536 + ct * 128;
            *(float4*)(dst + (tc << 2))      = make_float4(acc[i][0], acc[i][1], acc[i][2], acc[i][3]);
            *(float4*)(dst + 64 + (tc << 2)) = make_float4(acc[i][4], acc[i][5], acc[i][6], acc[i][7]);
        }
    }
}

// ---------------------------------------------------------------------------
// Tree iou GEMM (small levels, n<=64): 64x64 tile, 4x4 micro. Internal only.
// ---------------------------------------------------------------------------
__global__ void __launch_bounds__(256)
iou_small_k(const int* __restrict__ node_feat, const int* __restrict__ mask,
            const float* __restrict__ emb, const float* __restrict__ Wiou,
            const float* __restrict__ Uiou, const float* __restrict__ hbuf,
            float* __restrict__ iou_out, int first, int n, int nshift)
{
    const int rows = B_ * n;
    const int rt = blockIdx.x, ct = blockIdx.y;
    const int tid = threadIdx.x;
    const int tr = tid >> 4, tc = tid & 15;

    __shared__ __align__(16) float As[8][72];
    __shared__ __align__(16) float Bs[8][72];

    float acc[4][4];
#pragma unroll
    for (int i = 0; i < 4; ++i)
#pragma unroll
        for (int j = 0; j < 4; ++j) acc[i][j] = 0.0f;

    const int srow = tid & 63, skq = tid >> 6;
    const int grow = rt * 64 + srow;
    const bool rvalid = grow < rows;
    int tok = 0; float mval = 0.f; int hoff1 = 0, hoff2 = 0;
    if (rvalid) {
        const int b = grow >> nshift, j = grow & (n - 1);
        const int node = first + j;
        tok  = node_feat[b * N_ + node];
        mval = (float)mask[b * N_ + node];
        hoff1 = (b * N_ + 2 * node + 1) * H_;
        hoff2 = hoff1 + H_;
    }
    const int gcol = ct * 64 + srow;

    for (int kt = 0; kt < 96; ++kt) {
        const int k0 = kt << 3;
        {
            const int kg = k0 + (skq << 1);
            float2 v = make_float2(0.f, 0.f);
            if (rvalid) {
                if (kg < E_) {
                    float2 e = *(const float2*)(emb + tok * E_ + kg);
                    v.x = e.x * mval; v.y = e.y * mval;
                } else {
                    const int kk = kg - E_;
                    float2 h1 = *(const float2*)(hbuf + hoff1 + kk);
                    float2 h2 = *(const float2*)(hbuf + hoff2 + kk);
                    v.x = h1.x + h2.x; v.y = h1.y + h2.y;
                }
            }
            As[(skq << 1) + 0][srow] = v.x;
            As[(skq << 1) + 1][srow] = v.y;
        }
        {
            const int kg = k0 + (skq << 1);
            const float* s0 = (kg < E_) ? (Wiou + (size_t)kg * 1536 + gcol)
                                        : (Uiou + (size_t)(kg - E_) * 1536 + gcol);
            const float* s1 = ((kg + 1) < E_) ? (Wiou + (size_t)(kg + 1) * 1536 + gcol)
                                              : (Uiou + (size_t)(kg + 1 - E_) * 1536 + gcol);
            Bs[(skq << 1) + 0][srow] = *s0;
            Bs[(skq << 1) + 1][srow] = *s1;
        }
        __syncthreads();
#pragma unroll
        for (int kk = 0; kk < 8; ++kk) {
            float a[4], bb[4];
            *(float4*)&a[0]  = *(const float4*)&As[kk][tr << 2];
            *(float4*)&bb[0] = *(const float4*)&Bs[kk][tc << 2];
#pragma unroll
            for (int i = 0; i < 4; ++i)
#pragma unroll
                for (int j = 0; j < 4; ++j)
                    acc[i][j] = fmaf(a[i], bb[j], acc[i][j]);
        }
        __syncthreads();
    }
#pragma unroll
    for (int i = 0; i < 4; ++i) {
        const int r = rt * 64 + (tr << 2) + i;
        if (r < rows)
            *(float4*)(iou_out + (size_t)r * 1536 + ct * 64 + (tc << 2)) =
                make_float4(acc[i][0], acc[i][1], acc[i][2], acc[i][3]);
    }
}

// ---------------------------------------------------------------------------
// f-gate GEMM (large levels): 128x128 tile with fused c_agg epilogue.
// ---------------------------------------------------------------------------
__global__ void __launch_bounds__(256)
fagg_gemm_k(const float* __restrict__ hbuf, const float* __restrict__ cbuf,
            const float* __restrict__ Ufw, const float* __restrict__ Ufb,
            float* __restrict__ cagg, int first, int n, int nshift)
{
    const int rows = 64 * n;
    const int rt = blockIdx.x, ct = blockIdx.y;
    const int tid = threadIdx.x;
    const int tr = tid >> 4, tc = tid & 15;

    __shared__ __align__(16) float As[8][136];
    __shared__ __align__(16) float Bs[8][136];

    float acc[8][8];
#pragma unroll
    for (int i = 0; i < 8; ++i)
#pragma unroll
        for (int j = 0; j < 8; ++j) acc[i][j] = 0.0f;

    const int lrow = tid >> 1;
    const int lkq  = (tid & 1) << 2;
    const int grow = rt * 128 + lrow;
    const bool rvalid = grow < rows;
    int hoff = 0;
    if (rvalid) {
        const int bj = grow >> 1, s = grow & 1;
        const int b = bj >> nshift, j = bj & (n - 1);
        const int node = first + j;
        hoff = (b * N_ + 2 * node + 1 + s) * H_;
    }
    const int bk   = tid >> 5;
    const int bcol = (tid & 31) << 2;
    const int gcol = ct * 128 + bcol;

    for (int kt = 0; kt < 64; ++kt) {
        const int k0 = kt << 3;
        {
            const int kg = k0 + lkq;
            float4 v = make_float4(0.f, 0.f, 0.f, 0.f);
            if (rvalid) v = *(const float4*)(hbuf + hoff + kg);
            As[lkq + 0][lrow] = v.x;
            As[lkq + 1][lrow] = v.y;
            As[lkq + 2][lrow] = v.z;
            As[lkq + 3][lrow] = v.w;
        }
        {
            const int kg = k0 + bk;
            *(float4*)&Bs[bk][bcol] = *(const float4*)(Ufw + kg * H_ + gcol);
        }
        __syncthreads();
#pragma unroll
        for (int kk = 0; kk < 8; ++kk) {
            float a[8], bb[8];
            *(float4*)&a[0]  = *(const float4*)&As[kk][tr << 3];
            *(float4*)&a[4]  = *(const float4*)&As[kk][(tr << 3) + 4];
            *(float4*)&bb[0] = *(const float4*)&Bs[kk][tc << 2];
            *(float4*)&bb[4] = *(const float4*)&Bs[kk][(tc << 2) + 64];
#pragma unroll
            for (int i = 0; i < 8; ++i)
#pragma unroll
                for (int j = 0; j < 8; ++j)
                    acc[i][j] = fmaf(a[i], bb[j], acc[i][j]);
        }
        __syncthreads();
    }
#pragma unroll
    for (int p = 0; p < 4; ++p) {
        const int r0 = rt * 128 + (tr << 3) + 2 * p;
        if (r0 < rows) {
            const int bj = r0 >> 1;
            const int b = bj >> nshift, j = bj & (n - 1);
            const int node = first + j;
            const float* c1 = cbuf + (b * N_ + 2 * node + 1) * H_ + ct * 128;
            const float* c2 = c1 + H_;
            float* dst = cagg + bj * H_ + ct * 128;
#pragma unroll
            for (int g = 0; g < 2; ++g) {
                const int off = (g ? 64 : 0) + (tc << 2);
                const int jb = g * 4;
                float4 cc1 = *(const float4*)(c1 + off);
                float4 cc2 = *(const float4*)(c2 + off);
                float4 bbv = *(const float4*)(Ufb + ct * 128 + off);
                float4 res;
                res.x = sigf(acc[2*p][jb+0] + bbv.x) * cc1.x + sigf(acc[2*p+1][jb+0] + bbv.x) * cc2.x;
                res.y = sigf(acc[2*p][jb+1] + bbv.y) * cc1.y + sigf(acc[2*p+1][jb+1] + bbv.y) * cc2.y;
                res.z = sigf(acc[2*p][jb+2] + bbv.z) * cc1.z + sigf(acc[2*p+1][jb+2] + bbv.z) * cc2.z;
                res.w = sigf(acc[2*p][jb+3] + bbv.w) * cc1.w + sigf(acc[2*p+1][jb+3] + bbv.w) * cc2.w;
                *(float4*)(dst + off) = res;
            }
        }
    }
}

// ---------------------------------------------------------------------------
// f-gate GEMM (small levels, n<=64): 64x64 tile, 4x4 micro, fused epilogue.
// ---------------------------------------------------------------------------
__global__ void __launch_bounds__(256)
fagg_small_k(const float* __restrict__ hbuf, const float* __restrict__ cbuf,
             const float* __restrict__ Ufw, const float* __restrict__ Ufb,
             float* __restrict__ cagg, int first, int n, int nshift)
{
    const int rows = 64 * n;
    const int rt = blockIdx.x, ct = blockIdx.y;
    const int tid = threadIdx.x;
    const int tr = tid >> 4, tc = tid & 15;

    __shared__ __align__(16) float As[8][72];
    __shared__ __align__(16) float Bs[8][72];

    float acc[4][4];
#pragma unroll
    for (int i = 0; i < 4; ++i)
#pragma unroll
        for (int j = 0; j < 4; ++j) acc[i][j] = 0.0f;

    const int srow = tid & 63, skq = tid >> 6;
    const int grow = rt * 64 + srow;
    const bool rvalid = grow < rows;
    int hoff = 0;
    if (rvalid) {
        const int bj = grow >> 1, s = grow & 1;
        const int b = bj >> nshift, j = bj & (n - 1);
        const int node = first + j;
        hoff = (b * N_ + 2 * node + 1 + s) * H_;
    }
    const int gcol = ct * 64 + srow;

    for (int kt = 0; kt < 64; ++kt) {
        const int k0 = kt << 3;
        {
            const int kg = k0 + (skq << 1);
            float2 v = make_float2(0.f, 0.f);
            if (rvalid) v = *(const float2*)(hbuf + hoff + kg);
            As[(skq << 1) + 0][srow] = v.x;
            As[(skq << 1) + 1][srow] = v.y;
        }
        {
            const int kg = k0 + (skq << 1);
            Bs[(skq << 1) + 0][srow] = Ufw[(size_t)kg * H_ + gcol];
            Bs[(skq << 1) + 1][srow] = Ufw[(size_t)(kg + 1) * H_ + gcol];
        }
        __syncthreads();
#pragma unroll
        for (int kk = 0; kk < 8; ++kk) {
            float a[4], bb[4];
            *(float4*)&a[0]  = *(const float4*)&As[kk][tr << 2];
            *(float4*)&bb[0] = *(const float4*)&Bs[kk][tc << 2];
#pragma unroll
            for (int i = 0; i < 4; ++i)
#pragma unroll
                for (int j = 0; j < 4; ++j)
                    acc[i][j] = fmaf(a[i], bb[j], acc[i][j]);
        }
        __syncthreads();
    }
#pragma unroll
    for (int p = 0; p < 2; ++p) {
        const int r0 = rt * 64 + (tr << 2) + 2 * p;
        if (r0 < rows) {
            const int bj = r0 >> 1;
            const int b = bj >> nshift, j = bj & (n - 1);
            const int node = first + j;
            const float* c1 = cbuf + (b * N_ + 2 * node + 1) * H_ + ct * 64;
            const float* c2 = c1 + H_;
            float* dst = cagg + bj * H_ + ct * 64;
            const int off = tc << 2;
            float4 cc1 = *(const float4*)(c1 + off);
            float4 cc2 = *(const float4*)(c2 + off);
            float4 bbv = *(const float4*)(Ufb + ct * 64 + off);
            float4 res;
            res.x = sigf(acc[2*p][0] + bbv.x) * cc1.x + sigf(acc[2*p+1][0] + bbv.x) * cc2.x;
            res.y = sigf(acc[2*p][1] + bbv.y) * cc1.y + sigf(acc[2*p+1][1] + bbv.y) * cc2.y;
            res.z = sigf(acc[2*p][2] + bbv.z) * cc1.z + sigf(acc[2*p+1][2] + bbv.z) * cc2.z;
            res.w = sigf(acc[2*p][3] + bbv.w) * cc1.w + sigf(acc[2*p+1][3] + bbv.w) * cc2.w;
            *(float4*)(dst + off) = res;
        }
    }
}

// ---------------------------------------------------------------------------
template<bool LEAF>
__global__ void apply_node_k(const float* __restrict__ iou,
                             const float* __restrict__ b_iou,
                             const float* __restrict__ cagg,
                             float* __restrict__ hbuf, float* __restrict__ cbuf,
                             int first, int n, int nshift)
{
    const int gid = blockIdx.x * 256 + threadIdx.x;
    if (gid >= B_ * n * 128) return;
    const int r = gid >> 7, col = (gid & 127) << 2;
    const float* row = iou + (size_t)r * 1536;
    float4 iv = *(const float4*)(row + col);
    float4 ov = *(const float4*)(row + 512 + col);
    float4 uv = *(const float4*)(row + 1024 + col);
    float4 bi = *(const float4*)(b_iou + col);
    float4 bo = *(const float4*)(b_iou + 512 + col);
    float4 bu = *(const float4*)(b_iou + 1024 + col);
    float4 ca = make_float4(0.f, 0.f, 0.f, 0.f);
    if (!LEAF) ca = *(const float4*)(cagg + r * H_ + col);
    float4 cn, hn;
    cn.x = sigf(iv.x + bi.x) * tanhf(uv.x + bu.x) + ca.x;
    cn.y = sigf(iv.y + bi.y) * tanhf(uv.y + bu.y) + ca.y;
    cn.z = sigf(iv.z + bi.z) * tanhf(uv.z + bu.z) + ca.z;
    cn.w = sigf(iv.w + bi.w) * tanhf(uv.w + bu.w) + ca.w;
    hn.x = sigf(ov.x + bo.x) * tanhf(cn.x);
    hn.y = sigf(ov.y + bo.y) * tanhf(cn.y);
    hn.z = sigf(ov.z + bo.z) * tanhf(cn.z);
    hn.w = sigf(ov.w + bo.w) * tanhf(cn.w);
    const int b = r >> nshift, j = r & (n - 1);
    const int node = first + j;
    const size_t o = (size_t)(b * N_ + node) * H_ + col;
    *(float4*)(cbuf + o) = cn;
    *(float4*)(hbuf + o) = hn;
}

// ---------------------------------------------------------------------------
// two-stage mean over nodes
// ---------------------------------------------------------------------------
__global__ void mean_part_k(const float* __restrict__ hbuf, float* __restrict__ mpart)
{
    const int bid = blockIdx.x;               // 256 = 32 b x 8 chunks
    const int b = bid >> 3, chunk = bid & 7;
    const int tid = threadIdx.x;
    const int n0 = chunk * 128;
    const int n1 = (n0 + 128 < N_) ? (n0 + 128) : N_;
    float s0 = 0.f, s1 = 0.f;
    for (int nn = n0; nn < n1; ++nn) {
        const float* p = hbuf + (size_t)(b * N_ + nn) * H_;
        s0 += p[tid];
        s1 += p[tid + 256];
    }
    mpart[(bid << 9) + tid]       = s0;
    mpart[(bid << 9) + tid + 256] = s1;
}

__global__ void mean_fin_k(const float* __restrict__ mpart, float* __restrict__ mf)
{
    const int gid = blockIdx.x * 256 + threadIdx.x;   // 16384
    const int b = gid >> 9, k = gid & 511;
    float s = 0.f;
#pragma unroll
    for (int c = 0; c < 8; ++c) s += mpart[(((b << 3) + c) << 9) + k];
    mf[gid] = s * (1.0f / 1023.0f);
}

__global__ void hidcel_k(const float* __restrict__ mf,
                         const float* __restrict__ hw, const float* __restrict__ hb,
                         const float* __restrict__ cw, const float* __restrict__ cb,
                         float* __restrict__ hs0, float* __restrict__ cs)
{
    const int gid = blockIdx.x * 256 + threadIdx.x;   // 32768
    const int which = gid >> 14;
    const int b = (gid >> 9) & 31, l = gid & 511;
    const float* W = which ? cw : hw;
    float acc = which ? cb[l] : hb[l];
#pragma unroll 8
    for (int k = 0; k < H_; ++k) acc = fmaf(mf[b * H_ + k], W[k * H_ + l], acc);
    if (which) cs[b * H_ + l] = acc; else hs0[b * H_ + l] = acc;
}

// ---------------------------------------------------------------------------
// persistent decoder v2: 512 blocks (2/CU), LDS 77 KB, 2 phases + 2 barriers
// per step. Phase A (256 blocks): token argmax finalize + gates via L2-gather
// (8b x 8k lanes, shfl K-reduce) -> hs,cs. Phase B (500 blocks): logits 64
// cols/block full-K with triple-buffered fc_w prefetch + in-wave argmax.
// ---------------------------------------------------------------------------
__global__ void __launch_bounds__(256, 2)
decoder_k(const float* __restrict__ emb, const float* __restrict__ W_ih,
          const float* __restrict__ W_hh, const float* __restrict__ b_ih,
          const float* __restrict__ b_hh, const float* __restrict__ fc_w,
          const float* __restrict__ fc_b, float* __restrict__ hsb,
          float* __restrict__ csb, float* __restrict__ out,
          float* __restrict__ pval, int* __restrict__ pidx, unsigned* bar)
{
    __shared__ __align__(16) float sm[512 * 36];   // 73,728 B staging
    __shared__ float rv[256];
    __shared__ int   ri[256];
    __shared__ int   tokS[B_];
    const int bid = blockIdx.x, tid = threadIdx.x;
    const int w = tid >> 6, lane = tid & 63;

    for (int t = 1; t < T_; ++t) {
        const float* hs_in  = hsb + ((t - 1) & 1) * (B_ * H_);
        float*       hs_out = hsb + (t & 1) * (B_ * H_);

        // ================= phase A: gates =================
        if (bid < 256) {
            if (t == 1) {
                if (tid < B_) tokS[tid] = 0;
            } else {
                const int b = tid & 31, ch = tid >> 5;
                float bv = -INFINITY; int bi2 = 0x7fffffff;
                for (int p = ch; p < NBL; p += 8) {
                    const float v = pval[b * NBL + p];
                    const int  ix = pidx[b * NBL + p];
                    if (v > bv || (v == bv && ix < bi2)) { bv = v; bi2 = ix; }
                }
                rv[tid] = bv; ri[tid] = bi2;
                __syncthreads();
                if (tid < B_) {
                    float Bv = -INFINITY; int Bi = 0x7fffffff;
#pragma unroll
                    for (int c2 = 0; c2 < 8; ++c2) {
                        const float v = rv[c2 * 32 + tid];
                        const int  ix = ri[c2 * 32 + tid];
                        if (v > Bv || (v == Bv && ix < Bi)) { Bv = v; Bi = ix; }
                    }
                    tokS[tid] = Bi;
                }
            }
            __syncthreads();

            const int b     = (w << 3) + (lane >> 3);
            const int klane = lane & 7;
            const int l0    = bid << 1;
            const float* xrow = emb + (size_t)tokS[b] * E_;
            const float* hrow = hs_in + b * H_;
            float aix = 0.f, aiy = 0.f, afx = 0.f, afy = 0.f;
            float agx = 0.f, agy = 0.f, aox = 0.f, aoy = 0.f;
            for (int kc = 0; kc < 96; ++kc) {
                const int k = (kc << 3) + klane;
                float xv; const float* p;
                if (k < E_) { xv = xrow[k];       p = W_ih + (size_t)k * 2048 + l0; }
                else        { xv = hrow[k - E_];  p = W_hh + (size_t)(k - E_) * 2048 + l0; }
                const float2 wi = *(const float2*)p;
                const float2 wf = *(const float2*)(p + 512);
                const float2 wg = *(const float2*)(p + 1024);
                const float2 wo = *(const float2*)(p + 1536);
                aix = fmaf(xv, wi.x, aix); aiy = fmaf(xv, wi.y, aiy);
                afx = fmaf(xv, wf.x, afx); afy = fmaf(xv, wf.y, afy);
                agx = fmaf(xv, wg.x, agx); agy = fmaf(xv, wg.y, agy);
                aox = fmaf(xv, wo.x, aox); aoy = fmaf(xv, wo.y, aoy);
            }
#pragma unroll
            for (int d = 1; d < 8; d <<= 1) {
                aix += __shfl_xor(aix, d); aiy += __shfl_xor(aiy, d);
                afx += __shfl_xor(afx, d); afy += __shfl_xor(afy, d);
                agx += __shfl_xor(agx, d); agy += __shfl_xor(agy, d);
                aox += __shfl_xor(aox, d); aoy += __shfl_xor(aoy, d);
            }
            if (klane == 0) {
#pragma unroll
                for (int li = 0; li < 2; ++li) {
                    const int l = l0 + li;
                    const float gi = (li ? aiy : aix) + b_ih[l]        + b_hh[l];
                    const float gf = (li ? afy : afx) + b_ih[512 + l]  + b_hh[512 + l];
                    const float gg = (li ? agy : agx) + b_ih[1024 + l] + b_hh[1024 + l];
                    const float go = (li ? aoy : aox) + b_ih[1536 + l] + b_hh[1536 + l];
                    const float co = csb[b * H_ + l];
                    const float cn = sigf(gf) * co + sigf(gi) * tanhf(gg);
                    csb[b * H_ + l] = cn;
                    hs_out[b * H_ + l] = sigf(go) * tanhf(cn);
                }
            }
        }
        gridbar(bar + 2 * t - 2);

        // ================= phase B: logits =================
        if (bid < NBL) {
            for (int idx = tid; idx < B_ * H_; idx += 256) {
                const int b2 = idx >> 9, k = idx & 511;
                sm[k * 36 + b2] = hs_out[b2 * H_ + k];
            }
            __syncthreads();

            const int col = (bid << 6) + lane;
            float acc[8];
#pragma unroll
            for (int i = 0; i < 8; ++i) acc[i] = 0.f;

            const float* wp = fc_w + col;
            const float* hbase = sm + (w << 3);
            float wreg[8], wn1[8], wn2[8];
#pragma unroll
            for (int j = 0; j < 8; ++j) wreg[j] = wp[(size_t)j * V_];
#pragma unroll
            for (int j = 0; j < 8; ++j) wn1[j]  = wp[(size_t)(8 + j) * V_];
            for (int kb = 0; kb < 64; ++kb) {
                if (kb < 62) {
                    const float* wq = wp + (size_t)((kb + 2) << 3) * V_;
#pragma unroll
                    for (int j = 0; j < 8; ++j) wn2[j] = wq[(size_t)j * V_];
                }
#pragma unroll
                for (int j = 0; j < 8; ++j) {
                    const float* hq = hbase + ((kb << 3) + j) * 36;
                    float hv[8];
                    *(float4*)&hv[0] = *(const float4*)(hq);
                    *(float4*)&hv[4] = *(const float4*)(hq + 4);
#pragma unroll
                    for (int i = 0; i < 8; ++i)
                        acc[i] = fmaf(hv[i], wreg[j], acc[i]);
                }
#pragma unroll
                for (int j = 0; j < 8; ++j) { wreg[j] = wn1[j]; wn1[j] = wn2[j]; }
            }

            const float bias = fc_b[col];
            float* out_t = out + (size_t)t * (B_ * V_);
#pragma unroll
            for (int i = 0; i < 8; ++i) {
                const float v = acc[i] + bias;
                out_t[(size_t)((w << 3) + i) * V_ + col] = v;
                float bv = v; int bi = col;
#pragma unroll
                for (int d = 32; d > 0; d >>= 1) {
                    const float ov = __shfl_xor(bv, d);
                    const int   oi = __shfl_xor(bi, d);
                    if (ov > bv || (ov == bv && oi < bi)) { bv = ov; bi = oi; }
                }
                if (lane == 0) {
                    pval[((w << 3) + i) * NBL + bid] = bv;
                    pidx[((w << 3) + i) * NBL + bid] = bi;
                }
            }
        }
        gridbar(bar + 2 * t - 1);
    }
}

// ---------------------------------------------------------------------------
extern "C" void kernel_launch(void* const* d_in, const int* in_sizes, int n_in,
                              void* d_out, int out_size, void* d_ws, size_t ws_size,
                              hipStream_t stream)
{
    (void)in_sizes; (void)n_in; (void)out_size; (void)ws_size;
    const int*   node_feat = (const int*)  d_in[0];
    const int*   mask      = (const int*)  d_in[1];
    const float* emb       = (const float*)d_in[2];
    const float* W_iou     = (const float*)d_in[3];
    const float* U_iou     = (const float*)d_in[4];
    const float* b_iou     = (const float*)d_in[5];
    const float* U_f_w     = (const float*)d_in[6];
    const float* U_f_b     = (const float*)d_in[7];
    const float* hid_fc_w  = (const float*)d_in[8];
    const float* hid_fc_b  = (const float*)d_in[9];
    const float* cell_fc_w = (const float*)d_in[10];
    const float* cell_fc_b = (const float*)d_in[11];
    const float* W_ih      = (const float*)d_in[12];
    const float* W_hh      = (const float*)d_in[13];
    const float* b_ih      = (const float*)d_in[14];
    const float* b_hh      = (const float*)d_in[15];
    const float* fc_w      = (const float*)d_in[16];
    const float* fc_b      = (const float*)d_in[17];
    float* out = (float*)d_out;

    float* ws      = (float*)d_ws;
    float* iou_buf = ws;                      // 12,582,912 (8192 x 1536)
    float* cagg    = ws + 12582912;           //  4,194,304
    float* hbuf    = ws + 16777216;           // 16,760,832
    float* cbuf    = ws + 33538048;           // 16,760,832
    float* mf      = ws + 50298880;           //     16,384
    float* hsb     = ws + 50315264;           //     32,768 (ping-pong)
    float* csb     = ws + 50348032;           //     16,384
    float* pval    = ws + 50364416;           //     16,000 (32 x 500)
    int*   pidx    = (int*)(ws + 50380416);   //     16,000
    // after the tree, iou_buf is dead -> reuse for mean partials + barriers
    float*    mpart = iou_buf;                        // 131,072
    unsigned* bar   = (unsigned*)(iou_buf + 131072);  //      128

    // ---- tree: leaves (2 chunks of 256 nodes) ----
    for (int chunk = 0; chunk < 2; ++chunk) {
        const int first = 511 + 256 * chunk;
        dim3 g(64, 12);
        iou_gemm_k<true><<<g, 256, 0, stream>>>(node_feat, mask, emb, W_iou, U_iou,
                                                hbuf, iou_buf, first, 256, 8);
        apply_node_k<true><<<4096, 256, 0, stream>>>(iou_buf, b_iou, cagg,
                                                     hbuf, cbuf, first, 256, 8);
    }
    // ---- tree: internal levels ----
    for (int d = 8; d >= 0; --d) {
        const int n = 1 << d, first = n - 1;
        if (n <= 64) {
            dim3 gf((64 * n + 63) / 64, 8);
            fagg_small_k<<<gf, 256, 0, stream>>>(hbuf, cbuf, U_f_w, U_f_b, cagg, first, n, d);
            dim3 gi((32 * n + 63) / 64, 24);
            iou_small_k<<<gi, 256, 0, stream>>>(node_feat, mask, emb, W_iou, U_iou,
                                                hbuf, iou_buf, first, n, d);
        } else {
            dim3 gf((64 * n + 127) / 128, 4);
            fagg_gemm_k<<<gf, 256, 0, stream>>>(hbuf, cbuf, U_f_w, U_f_b, cagg, first, n, d);
            dim3 gi((32 * n + 127) / 128, 12);
            iou_gemm_k<false><<<gi, 256, 0, stream>>>(node_feat, mask, emb, W_iou, U_iou,
                                                      hbuf, iou_buf, first, n, d);
        }
        apply_node_k<false><<<16 * n, 256, 0, stream>>>(iou_buf, b_iou, cagg,
                                                        hbuf, cbuf, first, n, d);
    }
    // ---- barriers reset (iou_buf now dead) ----
    hipMemsetAsync(bar, 0, 128 * sizeof(unsigned), stream);
    // ---- pool + init ----
    mean_part_k<<<256, 256, 0, stream>>>(hbuf, mpart);
    mean_fin_k<<<64, 256, 0, stream>>>(mpart, mf);
    hidcel_k<<<128, 256, 0, stream>>>(mf, hid_fc_w, hid_fc_b, cell_fc_w, cell_fc_b, hsb, csb);
    // ---- out[0] = 0 ----
    hipMemsetAsync(d_out, 0, (size_t)B_ * V_ * sizeof(float), stream);
    // ---- persistent decoder ----
    decoder_k<<<DECB, 256, 0, stream>>>(emb, W_ih, W_hh, b_ih, b_hh, fc_w, fc_b,
                                        hsb, csb, out, pval, pidx, bar);
}

// Round 7
// 9205.374 us; speedup vs baseline: 3.1376x; 3.1376x over previous
//
#include <hip/hip_runtime.h>
#include <math.h>

#define B_ 32
#define N_ 1023
#define E_ 256
#define H_ 512
#define V_ 32000
#define T_ 64
#define NBL 500   // logits col-tiles (64 cols each)

__device__ __forceinline__ float sigf(float x) { return 1.0f / (1.0f + expf(-x)); }

// ---------------------------------------------------------------------------
// Tree iou GEMM (large levels): 128x128 tile, 8x8 micro.
// ---------------------------------------------------------------------------
template<bool LEAF>
__global__ void __launch_bounds__(256)
iou_gemm_k(const int* __restrict__ node_feat, const int* __restrict__ mask,
           const float* __restrict__ emb, const float* __restrict__ Wiou,
           const float* __restrict__ Uiou, const float* __restrict__ hbuf,
           float* __restrict__ iou_out, int first, int n, int nshift)
{
    const int rows = B_ * n;
    const int K = LEAF ? E_ : (E_ + H_);
    const int rt = blockIdx.x, ct = blockIdx.y;
    const int tid = threadIdx.x;
    const int tr = tid >> 4, tc = tid & 15;

    __shared__ __align__(16) float As[8][136];
    __shared__ __align__(16) float Bs[8][136];

    float acc[8][8];
#pragma unroll
    for (int i = 0; i < 8; ++i)
#pragma unroll
        for (int j = 0; j < 8; ++j) acc[i][j] = 0.0f;

    const int lrow = tid >> 1;
    const int lkq  = (tid & 1) << 2;
    const int grow = rt * 128 + lrow;
    const bool rvalid = grow < rows;
    int tok = 0; float mval = 0.0f; int hoff1 = 0, hoff2 = 0;
    if (rvalid) {
        const int b = grow >> nshift, j = grow & (n - 1);
        const int node = first + j;
        tok  = node_feat[b * N_ + node];
        mval = (float)mask[b * N_ + node];
        if (!LEAF) {
            hoff1 = (b * N_ + 2 * node + 1) * H_;
            hoff2 = hoff1 + H_;
        }
    }
    const int bk   = tid >> 5;
    const int bcol = (tid & 31) << 2;
    const int gcol = ct * 128 + bcol;

    const int nkt = K >> 3;
    for (int kt = 0; kt < nkt; ++kt) {
        const int k0 = kt << 3;
        {
            const int kg = k0 + lkq;
            float4 v = make_float4(0.f, 0.f, 0.f, 0.f);
            if (rvalid) {
                if (LEAF || kg < E_) {
                    float4 e = *(const float4*)(emb + tok * E_ + kg);
                    v.x = e.x * mval; v.y = e.y * mval; v.z = e.z * mval; v.w = e.w * mval;
                } else {
                    const int kk = kg - E_;
                    float4 h1 = *(const float4*)(hbuf + hoff1 + kk);
                    float4 h2 = *(const float4*)(hbuf + hoff2 + kk);
                    v.x = h1.x + h2.x; v.y = h1.y + h2.y;
                    v.z = h1.z + h2.z; v.w = h1.w + h2.w;
                }
            }
            As[lkq + 0][lrow] = v.x;
            As[lkq + 1][lrow] = v.y;
            As[lkq + 2][lrow] = v.z;
            As[lkq + 3][lrow] = v.w;
        }
        {
            const int kg = k0 + bk;
            const float* src = (LEAF || kg < E_) ? (Wiou + kg * 1536 + gcol)
                                                 : (Uiou + (kg - E_) * 1536 + gcol);
            *(float4*)&Bs[bk][bcol] = *(const float4*)src;
        }
        __syncthreads();
#pragma unroll
        for (int kk = 0; kk < 8; ++kk) {
            float a[8], bb[8];
            *(float4*)&a[0]  = *(const float4*)&As[kk][tr << 3];
            *(float4*)&a[4]  = *(const float4*)&As[kk][(tr << 3) + 4];
            *(float4*)&bb[0] = *(const float4*)&Bs[kk][tc << 2];
            *(float4*)&bb[4] = *(const float4*)&Bs[kk][(tc << 2) + 64];
#pragma unroll
            for (int i = 0; i < 8; ++i)
#pragma unroll
                for (int j = 0; j < 8; ++j)
                    acc[i][j] = fmaf(a[i], bb[j], acc[i][j]);
        }
        __syncthreads();
    }
#pragma unroll
    for (int i = 0; i < 8; ++i) {
        const int r = rt * 128 + (tr << 3) + i;
        if (r < rows) {
            float* dst = iou_out + (size_t)r * 1536 + ct * 128;
            *(float4*)(dst + (tc << 2))      = make_float4(acc[i][0], acc[i][1], acc[i][2], acc[i][3]);
            *(float4*)(dst + 64 + (tc << 2)) = make_float4(acc[i][4], acc[i][5], acc[i][6], acc[i][7]);
        }
    }
}

// ---------------------------------------------------------------------------
// Tree iou GEMM (small levels, n<=64): 64x64 tile, 4x4 micro. Internal only.
// ---------------------------------------------------------------------------
__global__ void __launch_bounds__(256)
iou_small_k(const int* __restrict__ node_feat, const int* __restrict__ mask,
            const float* __restrict__ emb, const float* __restrict__ Wiou,
            const float* __restrict__ Uiou, const float* __restrict__ hbuf,
            float* __restrict__ iou_out, int first, int n, int nshift)
{
    const int rows = B_ * n;
    const int rt = blockIdx.x, ct = blockIdx.y;
    const int tid = threadIdx.x;
    const int tr = tid >> 4, tc = tid & 15;

    __shared__ __align__(16) float As[8][72];
    __shared__ __align__(16) float Bs[8][72];

    float acc[4][4];
#pragma unroll
    for (int i = 0; i < 4; ++i)
#pragma unroll
        for (int j = 0; j < 4; ++j) acc[i][j] = 0.0f;

    const int srow = tid & 63, skq = tid >> 6;
    const int grow = rt * 64 + srow;
    const bool rvalid = grow < rows;
    int tok = 0; float mval = 0.f; int hoff1 = 0, hoff2 = 0;
    if (rvalid) {
        const int b = grow >> nshift, j = grow & (n - 1);
        const int node = first + j;
        tok  = node_feat[b * N_ + node];
        mval = (float)mask[b * N_ + node];
        hoff1 = (b * N_ + 2 * node + 1) * H_;
        hoff2 = hoff1 + H_;
    }
    const int gcol = ct * 64 + srow;

    for (int kt = 0; kt < 96; ++kt) {
        const int k0 = kt << 3;
        {
            const int kg = k0 + (skq << 1);
            float2 v = make_float2(0.f, 0.f);
            if (rvalid) {
                if (kg < E_) {
                    float2 e = *(const float2*)(emb + tok * E_ + kg);
                    v.x = e.x * mval; v.y = e.y * mval;
                } else {
                    const int kk = kg - E_;
                    float2 h1 = *(const float2*)(hbuf + hoff1 + kk);
                    float2 h2 = *(const float2*)(hbuf + hoff2 + kk);
                    v.x = h1.x + h2.x; v.y = h1.y + h2.y;
                }
            }
            As[(skq << 1) + 0][srow] = v.x;
            As[(skq << 1) + 1][srow] = v.y;
        }
        {
            const int kg = k0 + (skq << 1);
            const float* s0 = (kg < E_) ? (Wiou + (size_t)kg * 1536 + gcol)
                                        : (Uiou + (size_t)(kg - E_) * 1536 + gcol);
            const float* s1 = ((kg + 1) < E_) ? (Wiou + (size_t)(kg + 1) * 1536 + gcol)
                                              : (Uiou + (size_t)(kg + 1 - E_) * 1536 + gcol);
            Bs[(skq << 1) + 0][srow] = *s0;
            Bs[(skq << 1) + 1][srow] = *s1;
        }
        __syncthreads();
#pragma unroll
        for (int kk = 0; kk < 8; ++kk) {
            float a[4], bb[4];
            *(float4*)&a[0]  = *(const float4*)&As[kk][tr << 2];
            *(float4*)&bb[0] = *(const float4*)&Bs[kk][tc << 2];
#pragma unroll
            for (int i = 0; i < 4; ++i)
#pragma unroll
                for (int j = 0; j < 4; ++j)
                    acc[i][j] = fmaf(a[i], bb[j], acc[i][j]);
        }
        __syncthreads();
    }
#pragma unroll
    for (int i = 0; i < 4; ++i) {
        const int r = rt * 64 + (tr << 2) + i;
        if (r < rows)
            *(float4*)(iou_out + (size_t)r * 1536 + ct * 64 + (tc << 2)) =
                make_float4(acc[i][0], acc[i][1], acc[i][2], acc[i][3]);
    }
}

// ---------------------------------------------------------------------------
// f-gate GEMM (large levels): 128x128 tile with fused c_agg epilogue.
// ---------------------------------------------------------------------------
__global__ void __launch_bounds__(256)
fagg_gemm_k(const float* __restrict__ hbuf, const float* __restrict__ cbuf,
            const float* __restrict__ Ufw, const float* __restrict__ Ufb,
            float* __restrict__ cagg, int first, int n, int nshift)
{
    const int rows = 64 * n;
    const int rt = blockIdx.x, ct = blockIdx.y;
    const int tid = threadIdx.x;
    const int tr = tid >> 4, tc = tid & 15;

    __shared__ __align__(16) float As[8][136];
    __shared__ __align__(16) float Bs[8][136];

    float acc[8][8];
#pragma unroll
    for (int i = 0; i < 8; ++i)
#pragma unroll
        for (int j = 0; j < 8; ++j) acc[i][j] = 0.0f;

    const int lrow = tid >> 1;
    const int lkq  = (tid & 1) << 2;
    const int grow = rt * 128 + lrow;
    const bool rvalid = grow < rows;
    int hoff = 0;
    if (rvalid) {
        const int bj = grow >> 1, s = grow & 1;
        const int b = bj >> nshift, j = bj & (n - 1);
        const int node = first + j;
        hoff = (b * N_ + 2 * node + 1 + s) * H_;
    }
    const int bk   = tid >> 5;
    const int bcol = (tid & 31) << 2;
    const int gcol = ct * 128 + bcol;

    for (int kt = 0; kt < 64; ++kt) {
        const int k0 = kt << 3;
        {
            const int kg = k0 + lkq;
            float4 v = make_float4(0.f, 0.f, 0.f, 0.f);
            if (rvalid) v = *(const float4*)(hbuf + hoff + kg);
            As[lkq + 0][lrow] = v.x;
            As[lkq + 1][lrow] = v.y;
            As[lkq + 2][lrow] = v.z;
            As[lkq + 3][lrow] = v.w;
        }
        {
            const int kg = k0 + bk;
            *(float4*)&Bs[bk][bcol] = *(const float4*)(Ufw + kg * H_ + gcol);
        }
        __syncthreads();
#pragma unroll
        for (int kk = 0; kk < 8; ++kk) {
            float a[8], bb[8];
            *(float4*)&a[0]  = *(const float4*)&As[kk][tr << 3];
            *(float4*)&a[4]  = *(const float4*)&As[kk][(tr << 3) + 4];
            *(float4*)&bb[0] = *(const float4*)&Bs[kk][tc << 2];
            *(float4*)&bb[4] = *(const float4*)&Bs[kk][(tc << 2) + 64];
#pragma unroll
            for (int i = 0; i < 8; ++i)
#pragma unroll
                for (int j = 0; j < 8; ++j)
                    acc[i][j] = fmaf(a[i], bb[j], acc[i][j]);
        }
        __syncthreads();
    }
#pragma unroll
    for (int p = 0; p < 4; ++p) {
        const int r0 = rt * 128 + (tr << 3) + 2 * p;
        if (r0 < rows) {
            const int bj = r0 >> 1;
            const int b = bj >> nshift, j = bj & (n - 1);
            const int node = first + j;
            const float* c1 = cbuf + (b * N_ + 2 * node + 1) * H_ + ct * 128;
            const float* c2 = c1 + H_;
            float* dst = cagg + bj * H_ + ct * 128;
#pragma unroll
            for (int g = 0; g < 2; ++g) {
                const int off = (g ? 64 : 0) + (tc << 2);
                const int jb = g * 4;
                float4 cc1 = *(const float4*)(c1 + off);
                float4 cc2 = *(const float4*)(c2 + off);
                float4 bbv = *(const float4*)(Ufb + ct * 128 + off);
                float4 res;
                res.x = sigf(acc[2*p][jb+0] + bbv.x) * cc1.x + sigf(acc[2*p+1][jb+0] + bbv.x) * cc2.x;
                res.y = sigf(acc[2*p][jb+1] + bbv.y) * cc1.y + sigf(acc[2*p+1][jb+1] + bbv.y) * cc2.y;
                res.z = sigf(acc[2*p][jb+2] + bbv.z) * cc1.z + sigf(acc[2*p+1][jb+2] + bbv.z) * cc2.z;
                res.w = sigf(acc[2*p][jb+3] + bbv.w) * cc1.w + sigf(acc[2*p+1][jb+3] + bbv.w) * cc2.w;
                *(float4*)(dst + off) = res;
            }
        }
    }
}

// ---------------------------------------------------------------------------
// f-gate GEMM (small levels, n<=64): 64x64 tile, 4x4 micro, fused epilogue.
// ---------------------------------------------------------------------------
__global__ void __launch_bounds__(256)
fagg_small_k(const float* __restrict__ hbuf, const float* __restrict__ cbuf,
             const float* __restrict__ Ufw, const float* __restrict__ Ufb,
             float* __restrict__ cagg, int first, int n, int nshift)
{
    const int rows = 64 * n;
    const int rt = blockIdx.x, ct = blockIdx.y;
    const int tid = threadIdx.x;
    const int tr = tid >> 4, tc = tid & 15;

    __shared__ __align__(16) float As[8][72];
    __shared__ __align__(16) float Bs[8][72];

    float acc[4][4];
#pragma unroll
    for (int i = 0; i < 4; ++i)
#pragma unroll
        for (int j = 0; j < 4; ++j) acc[i][j] = 0.0f;

    const int srow = tid & 63, skq = tid >> 6;
    const int grow = rt * 64 + srow;
    const bool rvalid = grow < rows;
    int hoff = 0;
    if (rvalid) {
        const int bj = grow >> 1, s = grow & 1;
        const int b = bj >> nshift, j = bj & (n - 1);
        const int node = first + j;
        hoff = (b * N_ + 2 * node + 1 + s) * H_;
    }
    const int gcol = ct * 64 + srow;

    for (int kt = 0; kt < 64; ++kt) {
        const int k0 = kt << 3;
        {
            const int kg = k0 + (skq << 1);
            float2 v = make_float2(0.f, 0.f);
            if (rvalid) v = *(const float2*)(hbuf + hoff + kg);
            As[(skq << 1) + 0][srow] = v.x;
            As[(skq << 1) + 1][srow] = v.y;
        }
        {
            const int kg = k0 + (skq << 1);
            Bs[(skq << 1) + 0][srow] = Ufw[(size_t)kg * H_ + gcol];
            Bs[(skq << 1) + 1][srow] = Ufw[(size_t)(kg + 1) * H_ + gcol];
        }
        __syncthreads();
#pragma unroll
        for (int kk = 0; kk < 8; ++kk) {
            float a[4], bb[4];
            *(float4*)&a[0]  = *(const float4*)&As[kk][tr << 2];
            *(float4*)&bb[0] = *(const float4*)&Bs[kk][tc << 2];
#pragma unroll
            for (int i = 0; i < 4; ++i)
#pragma unroll
                for (int j = 0; j < 4; ++j)
                    acc[i][j] = fmaf(a[i], bb[j], acc[i][j]);
        }
        __syncthreads();
    }
#pragma unroll
    for (int p = 0; p < 2; ++p) {
        const int r0 = rt * 64 + (tr << 2) + 2 * p;
        if (r0 < rows) {
            const int bj = r0 >> 1;
            const int b = bj >> nshift, j = bj & (n - 1);
            const int node = first + j;
            const float* c1 = cbuf + (b * N_ + 2 * node + 1) * H_ + ct * 64;
            const float* c2 = c1 + H_;
            float* dst = cagg + bj * H_ + ct * 64;
            const int off = tc << 2;
            float4 cc1 = *(const float4*)(c1 + off);
            float4 cc2 = *(const float4*)(c2 + off);
            float4 bbv = *(const float4*)(Ufb + ct * 64 + off);
            float4 res;
            res.x = sigf(acc[2*p][0] + bbv.x) * cc1.x + sigf(acc[2*p+1][0] + bbv.x) * cc2.x;
            res.y = sigf(acc[2*p][1] + bbv.y) * cc1.y + sigf(acc[2*p+1][1] + bbv.y) * cc2.y;
            res.z = sigf(acc[2*p][2] + bbv.z) * cc1.z + sigf(acc[2*p+1][2] + bbv.z) * cc2.z;
            res.w = sigf(acc[2*p][3] + bbv.w) * cc1.w + sigf(acc[2*p+1][3] + bbv.w) * cc2.w;
            *(float4*)(dst + off) = res;
        }
    }
}

// ---------------------------------------------------------------------------
template<bool LEAF>
__global__ void apply_node_k(const float* __restrict__ iou,
                             const float* __restrict__ b_iou,
                             const float* __restrict__ cagg,
                             float* __restrict__ hbuf, float* __restrict__ cbuf,
                             int first, int n, int nshift)
{
    const int gid = blockIdx.x * 256 + threadIdx.x;
    if (gid >= B_ * n * 128) return;
    const int r = gid >> 7, col = (gid & 127) << 2;
    const float* row = iou + (size_t)r * 1536;
    float4 iv = *(const float4*)(row + col);
    float4 ov = *(const float4*)(row + 512 + col);
    float4 uv = *(const float4*)(row + 1024 + col);
    float4 bi = *(const float4*)(b_iou + col);
    float4 bo = *(const float4*)(b_iou + 512 + col);
    float4 bu = *(const float4*)(b_iou + 1024 + col);
    float4 ca = make_float4(0.f, 0.f, 0.f, 0.f);
    if (!LEAF) ca = *(const float4*)(cagg + r * H_ + col);
    float4 cn, hn;
    cn.x = sigf(iv.x + bi.x) * tanhf(uv.x + bu.x) + ca.x;
    cn.y = sigf(iv.y + bi.y) * tanhf(uv.y + bu.y) + ca.y;
    cn.z = sigf(iv.z + bi.z) * tanhf(uv.z + bu.z) + ca.z;
    cn.w = sigf(iv.w + bi.w) * tanhf(uv.w + bu.w) + ca.w;
    hn.x = sigf(ov.x + bo.x) * tanhf(cn.x);
    hn.y = sigf(ov.y + bo.y) * tanhf(cn.y);
    hn.z = sigf(ov.z + bo.z) * tanhf(cn.z);
    hn.w = sigf(ov.w + bo.w) * tanhf(cn.w);
    const int b = r >> nshift, j = r & (n - 1);
    const int node = first + j;
    const size_t o = (size_t)(b * N_ + node) * H_ + col;
    *(float4*)(cbuf + o) = cn;
    *(float4*)(hbuf + o) = hn;
}

// ---------------------------------------------------------------------------
// two-stage mean over nodes
// ---------------------------------------------------------------------------
__global__ void mean_part_k(const float* __restrict__ hbuf, float* __restrict__ mpart)
{
    const int bid = blockIdx.x;               // 256 = 32 b x 8 chunks
    const int b = bid >> 3, chunk = bid & 7;
    const int tid = threadIdx.x;
    const int n0 = chunk * 128;
    const int n1 = (n0 + 128 < N_) ? (n0 + 128) : N_;
    float s0 = 0.f, s1 = 0.f;
    for (int nn = n0; nn < n1; ++nn) {
        const float* p = hbuf + (size_t)(b * N_ + nn) * H_;
        s0 += p[tid];
        s1 += p[tid + 256];
    }
    mpart[(bid << 9) + tid]       = s0;
    mpart[(bid << 9) + tid + 256] = s1;
}

__global__ void mean_fin_k(const float* __restrict__ mpart, float* __restrict__ mf)
{
    const int gid = blockIdx.x * 256 + threadIdx.x;   // 16384
    const int b = gid >> 9, k = gid & 511;
    float s = 0.f;
#pragma unroll
    for (int c = 0; c < 8; ++c) s += mpart[(((b << 3) + c) << 9) + k];
    mf[gid] = s * (1.0f / 1023.0f);
}

__global__ void hidcel_k(const float* __restrict__ mf,
                         const float* __restrict__ hw, const float* __restrict__ hb,
                         const float* __restrict__ cw, const float* __restrict__ cb,
                         float* __restrict__ hs0, float* __restrict__ cs)
{
    const int gid = blockIdx.x * 256 + threadIdx.x;   // 32768
    const int which = gid >> 14;
    const int b = (gid >> 9) & 31, l = gid & 511;
    const float* W = which ? cw : hw;
    float acc = which ? cb[l] : hb[l];
#pragma unroll 8
    for (int k = 0; k < H_; ++k) acc = fmaf(mf[b * H_ + k], W[k * H_ + l], acc);
    if (which) cs[b * H_ + l] = acc; else hs0[b * H_ + l] = acc;
}

// ---------------------------------------------------------------------------
// decoder LSTM step v5: grid (64 l-tiles, 4 b-groups), 256 thr.
// Block: 8 l-cols x 8 b. LDS xh[768][9] = 27.6 KB -> ~4 blocks/CU.
// Wave: 8l x 8b lanes, K-split 4x192 across waves; LDS partial reduce.
// Also finalizes previous step's argmax for its 8 b's (absorbs fin kernel).
// ---------------------------------------------------------------------------
__global__ void __launch_bounds__(256)
lstm_step_k(const float* __restrict__ emb, const float* __restrict__ W_ih,
            const float* __restrict__ W_hh, const float* __restrict__ b_ih,
            const float* __restrict__ b_hh, const float* __restrict__ pval,
            const int* __restrict__ pidx, const float* __restrict__ hs_in,
            float* __restrict__ hs_out, float* __restrict__ cs, int t)
{
    __shared__ __align__(16) float xh[768][9];      // 27,648 B
    __shared__ __align__(16) float part[4][8][8][4]; // 4 KB
    __shared__ float rv[256];
    __shared__ int   ri[256];
    __shared__ int   tokS[8];
    const int tid = threadIdx.x;
    const int bg  = blockIdx.y;          // b-group (8 batches)

    // ---- finalize previous step's argmax for this block's 8 b's ----
    if (t == 1) {
        if (tid < 8) tokS[tid] = 0;
    } else {
        const int bs = tid >> 5, th = tid & 31;     // 8 b x 32 scanners
        const int b = bg * 8 + bs;
        float bv = -INFINITY; int bi = 0x7fffffff;
        for (int p = th; p < NBL; p += 32) {
            const float v = pval[b * NBL + p];
            const int  ix = pidx[b * NBL + p];
            if (v > bv || (v == bv && ix < bi)) { bv = v; bi = ix; }
        }
        rv[tid] = bv; ri[tid] = bi;
        __syncthreads();
        if (tid < 8) {
            float Bv = -INFINITY; int Bi = 0x7fffffff;
#pragma unroll
            for (int c = 0; c < 32; ++c) {
                const float v = rv[tid * 32 + c];
                const int  ix = ri[tid * 32 + c];
                if (v > Bv || (v == Bv && ix < Bi)) { Bv = v; Bi = ix; }
            }
            tokS[tid] = Bi;
        }
    }
    __syncthreads();

    // ---- stage x(emb) + h for 8 b's into xh[k][b] ----
#pragma unroll
    for (int b = 0; b < 8; ++b) {
        const int tok = tokS[b];
        if (tid < E_) xh[tid][b] = emb[(size_t)tok * E_ + tid];
        for (int k = tid; k < H_; k += 256)
            xh[E_ + k][b] = hs_in[(bg * 8 + b) * H_ + k];
    }
    __syncthreads();

    // ---- K-split gate partials: wave ks covers k in [ks*192, ks*192+192) ----
    const int ks = tid >> 6;
    const int lane = tid & 63;
    const int bi = lane >> 3, li = lane & 7;
    const int l = blockIdx.x * 8 + li;
    float ai = 0.f, af = 0.f, ag = 0.f, ao = 0.f;
    const int k0 = ks * 192;
    for (int kk = 0; kk < 192; ++kk) {
        const int k = k0 + kk;
        const float xv = xh[k][bi];
        const float* p = (k < E_) ? (W_ih + (size_t)k * 2048 + l)
                                  : (W_hh + (size_t)(k - E_) * 2048 + l);
        ai = fmaf(xv, p[0],    ai);
        af = fmaf(xv, p[512],  af);
        ag = fmaf(xv, p[1024], ag);
        ao = fmaf(xv, p[1536], ao);
    }
    part[ks][bi][li][0] = ai;
    part[ks][bi][li][1] = af;
    part[ks][bi][li][2] = ag;
    part[ks][bi][li][3] = ao;
    __syncthreads();

    // ---- reduce + cell update (64 threads) ----
    if (tid < 64) {
        const int b2 = tid >> 3, l2i = tid & 7;
        const int l2 = blockIdx.x * 8 + l2i;
        const int b = bg * 8 + b2;
        float s0 = 0.f, s1 = 0.f, s2 = 0.f, s3 = 0.f;
#pragma unroll
        for (int q = 0; q < 4; ++q) {
            s0 += part[q][b2][l2i][0];
            s1 += part[q][b2][l2i][1];
            s2 += part[q][b2][l2i][2];
            s3 += part[q][b2][l2i][3];
        }
        const float gi = s0 + b_ih[l2]        + b_hh[l2];
        const float gf = s1 + b_ih[512 + l2]  + b_hh[512 + l2];
        const float gg = s2 + b_ih[1024 + l2] + b_hh[1024 + l2];
        const float go = s3 + b_ih[1536 + l2] + b_hh[1536 + l2];
        const float co = cs[b * H_ + l2];
        const float cn = sigf(gf) * co + sigf(gi) * tanhf(gg);
        cs[b * H_ + l2] = cn;
        hs_out[b * H_ + l2] = sigf(go) * tanhf(cn);
    }
}

// ---------------------------------------------------------------------------
// logits v4: 500 blocks x 64 cols, full K, NO LDS staging. Wave handles 8 b's;
// hs read as wave-uniform float4 (scalar/L1 broadcast); fc_w triple-buffered.
// Writes out + per-block argmax partials via in-wave shfl.
// ---------------------------------------------------------------------------
__global__ void __launch_bounds__(256)
logits_k(const float* __restrict__ fc_w, const float* __restrict__ fc_b,
         const float* __restrict__ hs, float* __restrict__ out_t,
         float* __restrict__ pval, int* __restrict__ pidx)
{
    const int tid = threadIdx.x, bid = blockIdx.x;
    const int w = tid >> 6, lane = tid & 63;
    const int col = (bid << 6) + lane;
    const int b0 = w << 3;                       // wave's 8 batches

    const float4* hs4 = (const float4*)(hs + b0 * H_);   // rows b0..b0+7

    float acc[8];
#pragma unroll
    for (int i = 0; i < 8; ++i) acc[i] = 0.f;

    const float* wp = fc_w + col;
    float wreg[8], wn1[8], wn2[8];
#pragma unroll
    for (int j = 0; j < 8; ++j) wreg[j] = wp[(size_t)j * V_];
#pragma unroll
    for (int j = 0; j < 8; ++j) wn1[j]  = wp[(size_t)(8 + j) * V_];

    for (int kb = 0; kb < 64; ++kb) {
        if (kb < 62) {
            const float* wq = wp + (size_t)((kb + 2) << 3) * V_;
#pragma unroll
            for (int j = 0; j < 8; ++j) wn2[j] = wq[(size_t)j * V_];
        }
#pragma unroll
        for (int i = 0; i < 8; ++i) {
            const float4 h1 = hs4[i * 128 + (kb << 1)];
            const float4 h2 = hs4[i * 128 + (kb << 1) + 1];
            float a = acc[i];
            a = fmaf(h1.x, wreg[0], a);
            a = fmaf(h1.y, wreg[1], a);
            a = fmaf(h1.z, wreg[2], a);
            a = fmaf(h1.w, wreg[3], a);
            a = fmaf(h2.x, wreg[4], a);
            a = fmaf(h2.y, wreg[5], a);
            a = fmaf(h2.z, wreg[6], a);
            a = fmaf(h2.w, wreg[7], a);
            acc[i] = a;
        }
#pragma unroll
        for (int j = 0; j < 8; ++j) { wreg[j] = wn1[j]; wn1[j] = wn2[j]; }
    }

    const float bias = fc_b[col];
#pragma unroll
    for (int i = 0; i < 8; ++i) {
        const float v = acc[i] + bias;
        out_t[(size_t)(b0 + i) * V_ + col] = v;
        float bv = v; int bi = col;
#pragma unroll
        for (int d = 32; d > 0; d >>= 1) {
            const float ov = __shfl_xor(bv, d);
            const int   oi = __shfl_xor(bi, d);
            if (ov > bv || (ov == bv && oi < bi)) { bv = ov; bi = oi; }
        }
        if (lane == 0) {
            pval[(b0 + i) * NBL + bid] = bv;
            pidx[(b0 + i) * NBL + bid] = bi;
        }
    }
}

// ---------------------------------------------------------------------------
extern "C" void kernel_launch(void* const* d_in, const int* in_sizes, int n_in,
                              void* d_out, int out_size, void* d_ws, size_t ws_size,
                              hipStream_t stream)
{
    (void)in_sizes; (void)n_in; (void)out_size; (void)ws_size;
    const int*   node_feat = (const int*)  d_in[0];
    const int*   mask      = (const int*)  d_in[1];
    const float* emb       = (const float*)d_in[2];
    const float* W_iou     = (const float*)d_in[3];
    const float* U_iou     = (const float*)d_in[4];
    const float* b_iou     = (const float*)d_in[5];
    const float* U_f_w     = (const float*)d_in[6];
    const float* U_f_b     = (const float*)d_in[7];
    const float* hid_fc_w  = (const float*)d_in[8];
    const float* hid_fc_b  = (const float*)d_in[9];
    const float* cell_fc_w = (const float*)d_in[10];
    const float* cell_fc_b = (const float*)d_in[11];
    const float* W_ih      = (const float*)d_in[12];
    const float* W_hh      = (const float*)d_in[13];
    const float* b_ih      = (const float*)d_in[14];
    const float* b_hh      = (const float*)d_in[15];
    const float* fc_w      = (const float*)d_in[16];
    const float* fc_b      = (const float*)d_in[17];
    float* out = (float*)d_out;

    float* ws      = (float*)d_ws;
    float* iou_buf = ws;                      // 12,582,912 (8192 x 1536)
    float* cagg    = ws + 12582912;           //  4,194,304
    float* hbuf    = ws + 16777216;           // 16,760,832
    float* cbuf    = ws + 33538048;           // 16,760,832
    float* mf      = ws + 50298880;           //     16,384
    float* hsb     = ws + 50315264;           //     32,768 (ping-pong)
    float* csb     = ws + 50348032;           //     16,384
    float* pval    = ws + 50364416;           //     16,000 (32 x 500)
    int*   pidx    = (int*)(ws + 50380416);   //     16,000
    float* mpart   = iou_buf;                 //    131,072 (reuse after tree)

    // ---- tree: leaves (2 chunks of 256 nodes) ----
    for (int chunk = 0; chunk < 2; ++chunk) {
        const int first = 511 + 256 * chunk;
        dim3 g(64, 12);
        iou_gemm_k<true><<<g, 256, 0, stream>>>(node_feat, mask, emb, W_iou, U_iou,
                                                hbuf, iou_buf, first, 256, 8);
        apply_node_k<true><<<4096, 256, 0, stream>>>(iou_buf, b_iou, cagg,
                                                     hbuf, cbuf, first, 256, 8);
    }
    // ---- tree: internal levels ----
    for (int d = 8; d >= 0; --d) {
        const int n = 1 << d, first = n - 1;
        if (n <= 64) {
            dim3 gf((64 * n + 63) / 64, 8);
            fagg_small_k<<<gf, 256, 0, stream>>>(hbuf, cbuf, U_f_w, U_f_b, cagg, first, n, d);
            dim3 gi((32 * n + 63) / 64, 24);
            iou_small_k<<<gi, 256, 0, stream>>>(node_feat, mask, emb, W_iou, U_iou,
                                                hbuf, iou_buf, first, n, d);
        } else {
            dim3 gf((64 * n + 127) / 128, 4);
            fagg_gemm_k<<<gf, 256, 0, stream>>>(hbuf, cbuf, U_f_w, U_f_b, cagg, first, n, d);
            dim3 gi((32 * n + 127) / 128, 12);
            iou_gemm_k<false><<<gi, 256, 0, stream>>>(node_feat, mask, emb, W_iou, U_iou,
                                                      hbuf, iou_buf, first, n, d);
        }
        apply_node_k<false><<<16 * n, 256, 0, stream>>>(iou_buf, b_iou, cagg,
                                                        hbuf, cbuf, first, n, d);
    }
    // ---- pool + init ----
    mean_part_k<<<256, 256, 0, stream>>>(hbuf, mpart);
    mean_fin_k<<<64, 256, 0, stream>>>(mpart, mf);
    hidcel_k<<<128, 256, 0, stream>>>(mf, hid_fc_w, hid_fc_b, cell_fc_w, cell_fc_b, hsb, csb);
    // ---- out[0] = 0 ----
    hipMemsetAsync(d_out, 0, (size_t)B_ * V_ * sizeof(float), stream);
    // ---- decoder: 2 kernels per step ----
    for (int t = 1; t < T_; ++t) {
        const float* hs_in  = hsb + ((t - 1) & 1) * (B_ * H_);
        float*       hs_out = hsb + (t & 1) * (B_ * H_);
        dim3 gl(64, 4);
        lstm_step_k<<<gl, 256, 0, stream>>>(emb, W_ih, W_hh, b_ih, b_hh,
                                            pval, pidx, hs_in, hs_out, csb, t);
        logits_k<<<NBL, 256, 0, stream>>>(fc_w, fc_b, hs_out,
                                          out + (size_t)t * B_ * V_, pval, pidx);
    }
}

// Round 8
// 6996.832 us; speedup vs baseline: 4.1280x; 1.3156x over previous
//
#include <hip/hip_runtime.h>
#include <math.h>

#define B_ 32
#define N_ 1023
#define E_ 256
#define H_ 512
#define V_ 32000
#define T_ 64
#define NBL 250   // logits col-tiles (128 cols each)

__device__ __forceinline__ float sigf(float x) { return 1.0f / (1.0f + expf(-x)); }

// ---------------------------------------------------------------------------
// Tree iou GEMM (large levels): 128x128 tile, 8x8 micro.
// ---------------------------------------------------------------------------
template<bool LEAF>
__global__ void __launch_bounds__(256)
iou_gemm_k(const int* __restrict__ node_feat, const int* __restrict__ mask,
           const float* __restrict__ emb, const float* __restrict__ Wiou,
           const float* __restrict__ Uiou, const float* __restrict__ hbuf,
           float* __restrict__ iou_out, int first, int n, int nshift)
{
    const int rows = B_ * n;
    const int K = LEAF ? E_ : (E_ + H_);
    const int rt = blockIdx.x, ct = blockIdx.y;
    const int tid = threadIdx.x;
    const int tr = tid >> 4, tc = tid & 15;

    __shared__ __align__(16) float As[8][136];
    __shared__ __align__(16) float Bs[8][136];

    float acc[8][8];
#pragma unroll
    for (int i = 0; i < 8; ++i)
#pragma unroll
        for (int j = 0; j < 8; ++j) acc[i][j] = 0.0f;

    const int lrow = tid >> 1;
    const int lkq  = (tid & 1) << 2;
    const int grow = rt * 128 + lrow;
    const bool rvalid = grow < rows;
    int tok = 0; float mval = 0.0f; int hoff1 = 0, hoff2 = 0;
    if (rvalid) {
        const int b = grow >> nshift, j = grow & (n - 1);
        const int node = first + j;
        tok  = node_feat[b * N_ + node];
        mval = (float)mask[b * N_ + node];
        if (!LEAF) {
            hoff1 = (b * N_ + 2 * node + 1) * H_;
            hoff2 = hoff1 + H_;
        }
    }
    const int bk   = tid >> 5;
    const int bcol = (tid & 31) << 2;
    const int gcol = ct * 128 + bcol;

    const int nkt = K >> 3;
    for (int kt = 0; kt < nkt; ++kt) {
        const int k0 = kt << 3;
        {
            const int kg = k0 + lkq;
            float4 v = make_float4(0.f, 0.f, 0.f, 0.f);
            if (rvalid) {
                if (LEAF || kg < E_) {
                    float4 e = *(const float4*)(emb + tok * E_ + kg);
                    v.x = e.x * mval; v.y = e.y * mval; v.z = e.z * mval; v.w = e.w * mval;
                } else {
                    const int kk = kg - E_;
                    float4 h1 = *(const float4*)(hbuf + hoff1 + kk);
                    float4 h2 = *(const float4*)(hbuf + hoff2 + kk);
                    v.x = h1.x + h2.x; v.y = h1.y + h2.y;
                    v.z = h1.z + h2.z; v.w = h1.w + h2.w;
                }
            }
            As[lkq + 0][lrow] = v.x;
            As[lkq + 1][lrow] = v.y;
            As[lkq + 2][lrow] = v.z;
            As[lkq + 3][lrow] = v.w;
        }
        {
            const int kg = k0 + bk;
            const float* src = (LEAF || kg < E_) ? (Wiou + kg * 1536 + gcol)
                                                 : (Uiou + (kg - E_) * 1536 + gcol);
            *(float4*)&Bs[bk][bcol] = *(const float4*)src;
        }
        __syncthreads();
#pragma unroll
        for (int kk = 0; kk < 8; ++kk) {
            float a[8], bb[8];
            *(float4*)&a[0]  = *(const float4*)&As[kk][tr << 3];
            *(float4*)&a[4]  = *(const float4*)&As[kk][(tr << 3) + 4];
            *(float4*)&bb[0] = *(const float4*)&Bs[kk][tc << 2];
            *(float4*)&bb[4] = *(const float4*)&Bs[kk][(tc << 2) + 64];
#pragma unroll
            for (int i = 0; i < 8; ++i)
#pragma unroll
                for (int j = 0; j < 8; ++j)
                    acc[i][j] = fmaf(a[i], bb[j], acc[i][j]);
        }
        __syncthreads();
    }
#pragma unroll
    for (int i = 0; i < 8; ++i) {
        const int r = rt * 128 + (tr << 3) + i;
        if (r < rows) {
            float* dst = iou_out + (size_t)r * 1536 + ct * 128;
            *(float4*)(dst + (tc << 2))      = make_float4(acc[i][0], acc[i][1], acc[i][2], acc[i][3]);
            *(float4*)(dst + 64 + (tc << 2)) = make_float4(acc[i][4], acc[i][5], acc[i][6], acc[i][7]);
        }
    }
}

// ---------------------------------------------------------------------------
// Tree iou GEMM (small levels, n<=64): 64x64 tile, 4x4 micro. Internal only.
// ---------------------------------------------------------------------------
__global__ void __launch_bounds__(256)
iou_small_k(const int* __restrict__ node_feat, const int* __restrict__ mask,
            const float* __restrict__ emb, const float* __restrict__ Wiou,
            const float* __restrict__ Uiou, const float* __restrict__ hbuf,
            float* __restrict__ iou_out, int first, int n, int nshift)
{
    const int rows = B_ * n;
    const int rt = blockIdx.x, ct = blockIdx.y;
    const int tid = threadIdx.x;
    const int tr = tid >> 4, tc = tid & 15;

    __shared__ __align__(16) float As[8][72];
    __shared__ __align__(16) float Bs[8][72];

    float acc[4][4];
#pragma unroll
    for (int i = 0; i < 4; ++i)
#pragma unroll
        for (int j = 0; j < 4; ++j) acc[i][j] = 0.0f;

    const int srow = tid & 63, skq = tid >> 6;
    const int grow = rt * 64 + srow;
    const bool rvalid = grow < rows;
    int tok = 0; float mval = 0.f; int hoff1 = 0, hoff2 = 0;
    if (rvalid) {
        const int b = grow >> nshift, j = grow & (n - 1);
        const int node = first + j;
        tok  = node_feat[b * N_ + node];
        mval = (float)mask[b * N_ + node];
        hoff1 = (b * N_ + 2 * node + 1) * H_;
        hoff2 = hoff1 + H_;
    }
    const int gcol = ct * 64 + srow;

    for (int kt = 0; kt < 96; ++kt) {
        const int k0 = kt << 3;
        {
            const int kg = k0 + (skq << 1);
            float2 v = make_float2(0.f, 0.f);
            if (rvalid) {
                if (kg < E_) {
                    float2 e = *(const float2*)(emb + tok * E_ + kg);
                    v.x = e.x * mval; v.y = e.y * mval;
                } else {
                    const int kk = kg - E_;
                    float2 h1 = *(const float2*)(hbuf + hoff1 + kk);
                    float2 h2 = *(const float2*)(hbuf + hoff2 + kk);
                    v.x = h1.x + h2.x; v.y = h1.y + h2.y;
                }
            }
            As[(skq << 1) + 0][srow] = v.x;
            As[(skq << 1) + 1][srow] = v.y;
        }
        {
            const int kg = k0 + (skq << 1);
            const float* s0 = (kg < E_) ? (Wiou + (size_t)kg * 1536 + gcol)
                                        : (Uiou + (size_t)(kg - E_) * 1536 + gcol);
            const float* s1 = ((kg + 1) < E_) ? (Wiou + (size_t)(kg + 1) * 1536 + gcol)
                                              : (Uiou + (size_t)(kg + 1 - E_) * 1536 + gcol);
            Bs[(skq << 1) + 0][srow] = *s0;
            Bs[(skq << 1) + 1][srow] = *s1;
        }
        __syncthreads();
#pragma unroll
        for (int kk = 0; kk < 8; ++kk) {
            float a[4], bb[4];
            *(float4*)&a[0]  = *(const float4*)&As[kk][tr << 2];
            *(float4*)&bb[0] = *(const float4*)&Bs[kk][tc << 2];
#pragma unroll
            for (int i = 0; i < 4; ++i)
#pragma unroll
                for (int j = 0; j < 4; ++j)
                    acc[i][j] = fmaf(a[i], bb[j], acc[i][j]);
        }
        __syncthreads();
    }
#pragma unroll
    for (int i = 0; i < 4; ++i) {
        const int r = rt * 64 + (tr << 2) + i;
        if (r < rows)
            *(float4*)(iou_out + (size_t)r * 1536 + ct * 64 + (tc << 2)) =
                make_float4(acc[i][0], acc[i][1], acc[i][2], acc[i][3]);
    }
}

// ---------------------------------------------------------------------------
// f-gate GEMM (large levels): 128x128 tile with fused c_agg epilogue.
// ---------------------------------------------------------------------------
__global__ void __launch_bounds__(256)
fagg_gemm_k(const float* __restrict__ hbuf, const float* __restrict__ cbuf,
            const float* __restrict__ Ufw, const float* __restrict__ Ufb,
            float* __restrict__ cagg, int first, int n, int nshift)
{
    const int rows = 64 * n;
    const int rt = blockIdx.x, ct = blockIdx.y;
    const int tid = threadIdx.x;
    const int tr = tid >> 4, tc = tid & 15;

    __shared__ __align__(16) float As[8][136];
    __shared__ __align__(16) float Bs[8][136];

    float acc[8][8];
#pragma unroll
    for (int i = 0; i < 8; ++i)
#pragma unroll
        for (int j = 0; j < 8; ++j) acc[i][j] = 0.0f;

    const int lrow = tid >> 1;
    const int lkq  = (tid & 1) << 2;
    const int grow = rt * 128 + lrow;
    const bool rvalid = grow < rows;
    int hoff = 0;
    if (rvalid) {
        const int bj = grow >> 1, s = grow & 1;
        const int b = bj >> nshift, j = bj & (n - 1);
        const int node = first + j;
        hoff = (b * N_ + 2 * node + 1 + s) * H_;
    }
    const int bk   = tid >> 5;
    const int bcol = (tid & 31) << 2;
    const int gcol = ct * 128 + bcol;

    for (int kt = 0; kt < 64; ++kt) {
        const int k0 = kt << 3;
        {
            const int kg = k0 + lkq;
            float4 v = make_float4(0.f, 0.f, 0.f, 0.f);
            if (rvalid) v = *(const float4*)(hbuf + hoff + kg);
            As[lkq + 0][lrow] = v.x;
            As[lkq + 1][lrow] = v.y;
            As[lkq + 2][lrow] = v.z;
            As[lkq + 3][lrow] = v.w;
        }
        {
            const int kg = k0 + bk;
            *(float4*)&Bs[bk][bcol] = *(const float4*)(Ufw + kg * H_ + gcol);
        }
        __syncthreads();
#pragma unroll
        for (int kk = 0; kk < 8; ++kk) {
            float a[8], bb[8];
            *(float4*)&a[0]  = *(const float4*)&As[kk][tr << 3];
            *(float4*)&a[4]  = *(const float4*)&As[kk][(tr << 3) + 4];
            *(float4*)&bb[0] = *(const float4*)&Bs[kk][tc << 2];
            *(float4*)&bb[4] = *(const float4*)&Bs[kk][(tc << 2) + 64];
#pragma unroll
            for (int i = 0; i < 8; ++i)
#pragma unroll
                for (int j = 0; j < 8; ++j)
                    acc[i][j] = fmaf(a[i], bb[j], acc[i][j]);
        }
        __syncthreads();
    }
#pragma unroll
    for (int p = 0; p < 4; ++p) {
        const int r0 = rt * 128 + (tr << 3) + 2 * p;
        if (r0 < rows) {
            const int bj = r0 >> 1;
            const int b = bj >> nshift, j = bj & (n - 1);
            const int node = first + j;
            const float* c1 = cbuf + (b * N_ + 2 * node + 1) * H_ + ct * 128;
            const float* c2 = c1 + H_;
            float* dst = cagg + bj * H_ + ct * 128;
#pragma unroll
            for (int g = 0; g < 2; ++g) {
                const int off = (g ? 64 : 0) + (tc << 2);
                const int jb = g * 4;
                float4 cc1 = *(const float4*)(c1 + off);
                float4 cc2 = *(const float4*)(c2 + off);
                float4 bbv = *(const float4*)(Ufb + ct * 128 + off);
                float4 res;
                res.x = sigf(acc[2*p][jb+0] + bbv.x) * cc1.x + sigf(acc[2*p+1][jb+0] + bbv.x) * cc2.x;
                res.y = sigf(acc[2*p][jb+1] + bbv.y) * cc1.y + sigf(acc[2*p+1][jb+1] + bbv.y) * cc2.y;
                res.z = sigf(acc[2*p][jb+2] + bbv.z) * cc1.z + sigf(acc[2*p+1][jb+2] + bbv.z) * cc2.z;
                res.w = sigf(acc[2*p][jb+3] + bbv.w) * cc1.w + sigf(acc[2*p+1][jb+3] + bbv.w) * cc2.w;
                *(float4*)(dst + off) = res;
            }
        }
    }
}

// ---------------------------------------------------------------------------
// f-gate GEMM (small levels, n<=64): 64x64 tile, 4x4 micro, fused epilogue.
// ---------------------------------------------------------------------------
__global__ void __launch_bounds__(256)
fagg_small_k(const float* __restrict__ hbuf, const float* __restrict__ cbuf,
             const float* __restrict__ Ufw, const float* __restrict__ Ufb,
             float* __restrict__ cagg, int first, int n, int nshift)
{
    const int rows = 64 * n;
    const int rt = blockIdx.x, ct = blockIdx.y;
    const int tid = threadIdx.x;
    const int tr = tid >> 4, tc = tid & 15;

    __shared__ __align__(16) float As[8][72];
    __shared__ __align__(16) float Bs[8][72];

    float acc[4][4];
#pragma unroll
    for (int i = 0; i < 4; ++i)
#pragma unroll
        for (int j = 0; j < 4; ++j) acc[i][j] = 0.0f;

    const int srow = tid & 63, skq = tid >> 6;
    const int grow = rt * 64 + srow;
    const bool rvalid = grow < rows;
    int hoff = 0;
    if (rvalid) {
        const int bj = grow >> 1, s = grow & 1;
        const int b = bj >> nshift, j = bj & (n - 1);
        const int node = first + j;
        hoff = (b * N_ + 2 * node + 1 + s) * H_;
    }
    const int gcol = ct * 64 + srow;

    for (int kt = 0; kt < 64; ++kt) {
        const int k0 = kt << 3;
        {
            const int kg = k0 + (skq << 1);
            float2 v = make_float2(0.f, 0.f);
            if (rvalid) v = *(const float2*)(hbuf + hoff + kg);
            As[(skq << 1) + 0][srow] = v.x;
            As[(skq << 1) + 1][srow] = v.y;
        }
        {
            const int kg = k0 + (skq << 1);
            Bs[(skq << 1) + 0][srow] = Ufw[(size_t)kg * H_ + gcol];
            Bs[(skq << 1) + 1][srow] = Ufw[(size_t)(kg + 1) * H_ + gcol];
        }
        __syncthreads();
#pragma unroll
        for (int kk = 0; kk < 8; ++kk) {
            float a[4], bb[4];
            *(float4*)&a[0]  = *(const float4*)&As[kk][tr << 2];
            *(float4*)&bb[0] = *(const float4*)&Bs[kk][tc << 2];
#pragma unroll
            for (int i = 0; i < 4; ++i)
#pragma unroll
                for (int j = 0; j < 4; ++j)
                    acc[i][j] = fmaf(a[i], bb[j], acc[i][j]);
        }
        __syncthreads();
    }
#pragma unroll
    for (int p = 0; p < 2; ++p) {
        const int r0 = rt * 64 + (tr << 2) + 2 * p;
        if (r0 < rows) {
            const int bj = r0 >> 1;
            const int b = bj >> nshift, j = bj & (n - 1);
            const int node = first + j;
            const float* c1 = cbuf + (b * N_ + 2 * node + 1) * H_ + ct * 64;
            const float* c2 = c1 + H_;
            float* dst = cagg + bj * H_ + ct * 64;
            const int off = tc << 2;
            float4 cc1 = *(const float4*)(c1 + off);
            float4 cc2 = *(const float4*)(c2 + off);
            float4 bbv = *(const float4*)(Ufb + ct * 64 + off);
            float4 res;
            res.x = sigf(acc[2*p][0] + bbv.x) * cc1.x + sigf(acc[2*p+1][0] + bbv.x) * cc2.x;
            res.y = sigf(acc[2*p][1] + bbv.y) * cc1.y + sigf(acc[2*p+1][1] + bbv.y) * cc2.y;
            res.z = sigf(acc[2*p][2] + bbv.z) * cc1.z + sigf(acc[2*p+1][2] + bbv.z) * cc2.z;
            res.w = sigf(acc[2*p][3] + bbv.w) * cc1.w + sigf(acc[2*p+1][3] + bbv.w) * cc2.w;
            *(float4*)(dst + off) = res;
        }
    }
}

// ---------------------------------------------------------------------------
template<bool LEAF>
__global__ void apply_node_k(const float* __restrict__ iou,
                             const float* __restrict__ b_iou,
                             const float* __restrict__ cagg,
                             float* __restrict__ hbuf, float* __restrict__ cbuf,
                             int first, int n, int nshift)
{
    const int gid = blockIdx.x * 256 + threadIdx.x;
    if (gid >= B_ * n * 128) return;
    const int r = gid >> 7, col = (gid & 127) << 2;
    const float* row = iou + (size_t)r * 1536;
    float4 iv = *(const float4*)(row + col);
    float4 ov = *(const float4*)(row + 512 + col);
    float4 uv = *(const float4*)(row + 1024 + col);
    float4 bi = *(const float4*)(b_iou + col);
    float4 bo = *(const float4*)(b_iou + 512 + col);
    float4 bu = *(const float4*)(b_iou + 1024 + col);
    float4 ca = make_float4(0.f, 0.f, 0.f, 0.f);
    if (!LEAF) ca = *(const float4*)(cagg + r * H_ + col);
    float4 cn, hn;
    cn.x = sigf(iv.x + bi.x) * tanhf(uv.x + bu.x) + ca.x;
    cn.y = sigf(iv.y + bi.y) * tanhf(uv.y + bu.y) + ca.y;
    cn.z = sigf(iv.z + bi.z) * tanhf(uv.z + bu.z) + ca.z;
    cn.w = sigf(iv.w + bi.w) * tanhf(uv.w + bu.w) + ca.w;
    hn.x = sigf(ov.x + bo.x) * tanhf(cn.x);
    hn.y = sigf(ov.y + bo.y) * tanhf(cn.y);
    hn.z = sigf(ov.z + bo.z) * tanhf(cn.z);
    hn.w = sigf(ov.w + bo.w) * tanhf(cn.w);
    const int b = r >> nshift, j = r & (n - 1);
    const int node = first + j;
    const size_t o = (size_t)(b * N_ + node) * H_ + col;
    *(float4*)(cbuf + o) = cn;
    *(float4*)(hbuf + o) = hn;
}

// ---------------------------------------------------------------------------
// two-stage mean over nodes
// ---------------------------------------------------------------------------
__global__ void mean_part_k(const float* __restrict__ hbuf, float* __restrict__ mpart)
{
    const int bid = blockIdx.x;               // 256 = 32 b x 8 chunks
    const int b = bid >> 3, chunk = bid & 7;
    const int tid = threadIdx.x;
    const int n0 = chunk * 128;
    const int n1 = (n0 + 128 < N_) ? (n0 + 128) : N_;
    float s0 = 0.f, s1 = 0.f;
    for (int nn = n0; nn < n1; ++nn) {
        const float* p = hbuf + (size_t)(b * N_ + nn) * H_;
        s0 += p[tid];
        s1 += p[tid + 256];
    }
    mpart[(bid << 9) + tid]       = s0;
    mpart[(bid << 9) + tid + 256] = s1;
}

__global__ void mean_fin_k(const float* __restrict__ mpart, float* __restrict__ mf)
{
    const int gid = blockIdx.x * 256 + threadIdx.x;   // 16384
    const int b = gid >> 9, k = gid & 511;
    float s = 0.f;
#pragma unroll
    for (int c = 0; c < 8; ++c) s += mpart[(((b << 3) + c) << 9) + k];
    mf[gid] = s * (1.0f / 1023.0f);
}

__global__ void hidcel_k(const float* __restrict__ mf,
                         const float* __restrict__ hw, const float* __restrict__ hb,
                         const float* __restrict__ cw, const float* __restrict__ cb,
                         float* __restrict__ hs0, float* __restrict__ cs)
{
    const int gid = blockIdx.x * 256 + threadIdx.x;   // 32768
    const int which = gid >> 14;
    const int b = (gid >> 9) & 31, l = gid & 511;
    const float* W = which ? cw : hw;
    float acc = which ? cb[l] : hb[l];
#pragma unroll 8
    for (int k = 0; k < H_; ++k) acc = fmaf(mf[b * H_ + k], W[k * H_ + l], acc);
    if (which) cs[b * H_ + l] = acc; else hs0[b * H_ + l] = acc;
}

// ---------------------------------------------------------------------------
// decoder LSTM step: grid (64 l-tiles, 4 b-groups), 256 thr.
// Block: 8 l-cols x 8 b. LDS 27.6 KB -> ~4 blocks/CU. K-split 4x192 waves.
// Absorbs previous step's argmax finalize for its 8 b's.
// ---------------------------------------------------------------------------
__global__ void __launch_bounds__(256)
lstm_step_k(const float* __restrict__ emb, const float* __restrict__ W_ih,
            const float* __restrict__ W_hh, const float* __restrict__ b_ih,
            const float* __restrict__ b_hh, const float* __restrict__ pval,
            const int* __restrict__ pidx, const float* __restrict__ hs_in,
            float* __restrict__ hs_out, float* __restrict__ cs, int t)
{
    __shared__ __align__(16) float xh[768][9];       // 27,648 B
    __shared__ __align__(16) float part[4][8][8][4]; // 4 KB
    __shared__ float rv[256];
    __shared__ int   ri[256];
    __shared__ int   tokS[8];
    const int tid = threadIdx.x;
    const int bg  = blockIdx.y;          // b-group (8 batches)

    if (t == 1) {
        if (tid < 8) tokS[tid] = 0;
    } else {
        const int bs = tid >> 5, th = tid & 31;     // 8 b x 32 scanners
        const int b = bg * 8 + bs;
        float bv = -INFINITY; int bi = 0x7fffffff;
        for (int p = th; p < NBL; p += 32) {
            const float v = pval[b * NBL + p];
            const int  ix = pidx[b * NBL + p];
            if (v > bv || (v == bv && ix < bi)) { bv = v; bi = ix; }
        }
        rv[tid] = bv; ri[tid] = bi;
        __syncthreads();
        if (tid < 8) {
            float Bv = -INFINITY; int Bi = 0x7fffffff;
#pragma unroll
            for (int c = 0; c < 32; ++c) {
                const float v = rv[tid * 32 + c];
                const int  ix = ri[tid * 32 + c];
                if (v > Bv || (v == Bv && ix < Bi)) { Bv = v; Bi = ix; }
            }
            tokS[tid] = Bi;
        }
    }
    __syncthreads();

#pragma unroll
    for (int b = 0; b < 8; ++b) {
        const int tok = tokS[b];
        xh[tid][b] = emb[(size_t)tok * E_ + tid];
        for (int k = tid; k < H_; k += 256)
            xh[E_ + k][b] = hs_in[(bg * 8 + b) * H_ + k];
    }
    __syncthreads();

    const int ks = tid >> 6;
    const int lane = tid & 63;
    const int bi = lane >> 3, li = lane & 7;
    const int l = blockIdx.x * 8 + li;
    float ai = 0.f, af = 0.f, ag = 0.f, ao = 0.f;
    const int k0 = ks * 192;
    for (int kk = 0; kk < 192; ++kk) {
        const int k = k0 + kk;
        const float xv = xh[k][bi];
        const float* p = (k < E_) ? (W_ih + (size_t)k * 2048 + l)
                                  : (W_hh + (size_t)(k - E_) * 2048 + l);
        ai = fmaf(xv, p[0],    ai);
        af = fmaf(xv, p[512],  af);
        ag = fmaf(xv, p[1024], ag);
        ao = fmaf(xv, p[1536], ao);
    }
    part[ks][bi][li][0] = ai;
    part[ks][bi][li][1] = af;
    part[ks][bi][li][2] = ag;
    part[ks][bi][li][3] = ao;
    __syncthreads();

    if (tid < 64) {
        const int b2 = tid >> 3, l2i = tid & 7;
        const int l2 = blockIdx.x * 8 + l2i;
        const int b = bg * 8 + b2;
        float s0 = 0.f, s1 = 0.f, s2 = 0.f, s3 = 0.f;
#pragma unroll
        for (int q = 0; q < 4; ++q) {
            s0 += part[q][b2][l2i][0];
            s1 += part[q][b2][l2i][1];
            s2 += part[q][b2][l2i][2];
            s3 += part[q][b2][l2i][3];
        }
        const float gi = s0 + b_ih[l2]        + b_hh[l2];
        const float gf = s1 + b_ih[512 + l2]  + b_hh[512 + l2];
        const float gg = s2 + b_ih[1024 + l2] + b_hh[1024 + l2];
        const float go = s3 + b_ih[1536 + l2] + b_hh[1536 + l2];
        const float co = cs[b * H_ + l2];
        const float cn = sigf(gf) * co + sigf(gi) * tanhf(gg);
        cs[b * H_ + l2] = cn;
        hs_out[b * H_ + l2] = sigf(go) * tanhf(cn);
    }
}

// ---------------------------------------------------------------------------
// logits partial: grid (250 col-tiles, 4 k-quarters), 256 thr.
// Stage 128 hs rows in LDS (18.4 KB -> ~4+ blocks/CU). Wave owns 8 b's over
// its k-quarter, lane owns 2 cols (512B/wave request), 8-deep dbuf.
// partial[kq][b][V].
// ---------------------------------------------------------------------------
__global__ void __launch_bounds__(256)
logits_part_k(const float* __restrict__ fc_w, const float* __restrict__ hs,
              float* __restrict__ partial)
{
    __shared__ __align__(16) float sm[128 * 36];   // 18,432 B
    const int tid = threadIdx.x;
    const int blk = blockIdx.x;       // col tile (128 cols)
    const int kq  = blockIdx.y;       // k quarter (128 rows)

    for (int idx = tid; idx < B_ * 128; idx += 256) {
        const int b = idx & 31, k = idx >> 5;
        sm[k * 36 + b] = hs[b * H_ + kq * 128 + k];
    }
    __syncthreads();

    const int w8   = (tid >> 6) << 3;       // wave's b-chunk: 0,8,16,24
    const int lane = tid & 63;
    const int col  = (blk << 7) + (lane << 1);

    float acc[8][2];
#pragma unroll
    for (int i = 0; i < 8; ++i) { acc[i][0] = 0.f; acc[i][1] = 0.f; }

    const float* wp = fc_w + (size_t)(kq * 128) * V_ + col;
    const float* hp = sm + w8;
    float2 wreg[8];
#pragma unroll
    for (int j = 0; j < 8; ++j) wreg[j] = *(const float2*)(wp + (size_t)j * V_);
    for (int kb = 0; kb < 16; ++kb) {
        float2 wnxt[8];
        if (kb < 15) {
            const float* wq = wp + (size_t)((kb + 1) << 3) * V_;
#pragma unroll
            for (int j = 0; j < 8; ++j) wnxt[j] = *(const float2*)(wq + (size_t)j * V_);
        }
#pragma unroll
        for (int j = 0; j < 8; ++j) {
            const float* hq = hp + ((kb << 3) + j) * 36;   // wave-uniform LDS broadcast
            float hv[8];
            *(float4*)&hv[0] = *(const float4*)(hq);
            *(float4*)&hv[4] = *(const float4*)(hq + 4);
#pragma unroll
            for (int i = 0; i < 8; ++i) {
                acc[i][0] = fmaf(hv[i], wreg[j].x, acc[i][0]);
                acc[i][1] = fmaf(hv[i], wreg[j].y, acc[i][1]);
            }
        }
        if (kb < 15) {
#pragma unroll
            for (int j = 0; j < 8; ++j) wreg[j] = wnxt[j];
        }
    }
#pragma unroll
    for (int i = 0; i < 8; ++i) {
        float* dst = partial + (size_t)(kq * B_ + w8 + i) * V_ + col;
        *(float2*)dst = make_float2(acc[i][0], acc[i][1]);
    }
}

// ---------------------------------------------------------------------------
// logits finalize: 250 blocks. sum 4 quarters + bias -> out, block argmax.
// thread: (b = tid>>3, 16 cols); 8 threads/b reduce via LDS.
// ---------------------------------------------------------------------------
__global__ void __launch_bounds__(256)
logits_fin_k(const float* __restrict__ partial, const float* __restrict__ fc_b,
             float* __restrict__ out_t, float* __restrict__ pval,
             int* __restrict__ pidx)
{
    __shared__ float rv[256];
    __shared__ int   ri[256];
    const int tid = threadIdx.x, blk = blockIdx.x;
    const int b = tid >> 3, cg = (tid & 7) << 4;
    const int colbase = (blk << 7) + cg;

    const float* p0 = partial + (size_t)b * V_ + colbase;
    const float* p1 = partial + (size_t)(B_ + b) * V_ + colbase;
    const float* p2 = partial + (size_t)(2 * B_ + b) * V_ + colbase;
    const float* p3 = partial + (size_t)(3 * B_ + b) * V_ + colbase;
    const float* bp = fc_b + colbase;
    float* op = out_t + (size_t)b * V_ + colbase;

    float bv = -INFINITY; int bi = 0;
#pragma unroll
    for (int q = 0; q < 4; ++q) {
        float4 a0 = *(const float4*)(p0 + (q << 2));
        float4 a1 = *(const float4*)(p1 + (q << 2));
        float4 a2 = *(const float4*)(p2 + (q << 2));
        float4 a3 = *(const float4*)(p3 + (q << 2));
        float4 d  = *(const float4*)(bp + (q << 2));
        float4 v;
        v.x = a0.x + a1.x + a2.x + a3.x + d.x;
        v.y = a0.y + a1.y + a2.y + a3.y + d.y;
        v.z = a0.z + a1.z + a2.z + a3.z + d.z;
        v.w = a0.w + a1.w + a2.w + a3.w + d.w;
        *(float4*)(op + (q << 2)) = v;
        const int c0 = cg + (q << 2);
        if (v.x > bv) { bv = v.x; bi = c0 + 0; }
        if (v.y > bv) { bv = v.y; bi = c0 + 1; }
        if (v.z > bv) { bv = v.z; bi = c0 + 2; }
        if (v.w > bv) { bv = v.w; bi = c0 + 3; }
    }
    rv[tid] = bv; ri[tid] = bi;
    __syncthreads();
    if (tid < B_) {
        float Bv = -INFINITY; int Bi = 0;
#pragma unroll
        for (int q = 0; q < 8; ++q) {
            const float v = rv[(tid << 3) + q];     // ascending col order
            if (v > Bv) { Bv = v; Bi = ri[(tid << 3) + q]; }
        }
        pval[tid * NBL + blk] = Bv;
        pidx[tid * NBL + blk] = (blk << 7) + Bi;
    }
}

// ---------------------------------------------------------------------------
extern "C" void kernel_launch(void* const* d_in, const int* in_sizes, int n_in,
                              void* d_out, int out_size, void* d_ws, size_t ws_size,
                              hipStream_t stream)
{
    (void)in_sizes; (void)n_in; (void)out_size; (void)ws_size;
    const int*   node_feat = (const int*)  d_in[0];
    const int*   mask      = (const int*)  d_in[1];
    const float* emb       = (const float*)d_in[2];
    const float* W_iou     = (const float*)d_in[3];
    const float* U_iou     = (const float*)d_in[4];
    const float* b_iou     = (const float*)d_in[5];
    const float* U_f_w     = (const float*)d_in[6];
    const float* U_f_b     = (const float*)d_in[7];
    const float* hid_fc_w  = (const float*)d_in[8];
    const float* hid_fc_b  = (const float*)d_in[9];
    const float* cell_fc_w = (const float*)d_in[10];
    const float* cell_fc_b = (const float*)d_in[11];
    const float* W_ih      = (const float*)d_in[12];
    const float* W_hh      = (const float*)d_in[13];
    const float* b_ih      = (const float*)d_in[14];
    const float* b_hh      = (const float*)d_in[15];
    const float* fc_w      = (const float*)d_in[16];
    const float* fc_b      = (const float*)d_in[17];
    float* out = (float*)d_out;

    float* ws      = (float*)d_ws;
    float* iou_buf = ws;                      // 12,582,912 (8192 x 1536)
    float* cagg    = ws + 12582912;           //  4,194,304
    float* hbuf    = ws + 16777216;           // 16,760,832
    float* cbuf    = ws + 33538048;           // 16,760,832
    float* mf      = ws + 50298880;           //     16,384
    float* hsb     = ws + 50315264;           //     32,768 (ping-pong)
    float* csb     = ws + 50348032;           //     16,384
    float* pval    = ws + 50364416;           //      8,000 (32 x 250)
    int*   pidx    = (int*)(ws + 50372416);   //      8,000
    // after the tree, iou_buf is dead -> reuse for mean partials + logits partials
    float* mpart   = iou_buf;                 //    131,072
    float* partial = iou_buf + 262144;        //  4,096,000 (4 x 32 x 32000)

    // ---- tree: leaves (2 chunks of 256 nodes) ----
    for (int chunk = 0; chunk < 2; ++chunk) {
        const int first = 511 + 256 * chunk;
        dim3 g(64, 12);
        iou_gemm_k<true><<<g, 256, 0, stream>>>(node_feat, mask, emb, W_iou, U_iou,
                                                hbuf, iou_buf, first, 256, 8);
        apply_node_k<true><<<4096, 256, 0, stream>>>(iou_buf, b_iou, cagg,
                                                     hbuf, cbuf, first, 256, 8);
    }
    // ---- tree: internal levels ----
    for (int d = 8; d >= 0; --d) {
        const int n = 1 << d, first = n - 1;
        if (n <= 64) {
            dim3 gf((64 * n + 63) / 64, 8);
            fagg_small_k<<<gf, 256, 0, stream>>>(hbuf, cbuf, U_f_w, U_f_b, cagg, first, n, d);
            dim3 gi((32 * n + 63) / 64, 24);
            iou_small_k<<<gi, 256, 0, stream>>>(node_feat, mask, emb, W_iou, U_iou,
                                                hbuf, iou_buf, first, n, d);
        } else {
            dim3 gf((64 * n + 127) / 128, 4);
            fagg_gemm_k<<<gf, 256, 0, stream>>>(hbuf, cbuf, U_f_w, U_f_b, cagg, first, n, d);
            dim3 gi((32 * n + 127) / 128, 12);
            iou_gemm_k<false><<<gi, 256, 0, stream>>>(node_feat, mask, emb, W_iou, U_iou,
                                                      hbuf, iou_buf, first, n, d);
        }
        apply_node_k<false><<<16 * n, 256, 0, stream>>>(iou_buf, b_iou, cagg,
                                                        hbuf, cbuf, first, n, d);
    }
    // ---- pool + init ----
    mean_part_k<<<256, 256, 0, stream>>>(hbuf, mpart);
    mean_fin_k<<<64, 256, 0, stream>>>(mpart, mf);
    hidcel_k<<<128, 256, 0, stream>>>(mf, hid_fc_w, hid_fc_b, cell_fc_w, cell_fc_b, hsb, csb);
    // ---- out[0] = 0 ----
    hipMemsetAsync(d_out, 0, (size_t)B_ * V_ * sizeof(float), stream);
    // ---- decoder: 3 kernels per step ----
    for (int t = 1; t < T_; ++t) {
        const float* hs_in  = hsb + ((t - 1) & 1) * (B_ * H_);
        float*       hs_out = hsb + (t & 1) * (B_ * H_);
        dim3 gl(64, 4);
        lstm_step_k<<<gl, 256, 0, stream>>>(emb, W_ih, W_hh, b_ih, b_hh,
                                            pval, pidx, hs_in, hs_out, csb, t);
        dim3 gp(NBL, 4);
        logits_part_k<<<gp, 256, 0, stream>>>(fc_w, hs_out, partial);
        logits_fin_k<<<NBL, 256, 0, stream>>>(partial, fc_b,
                                              out + (size_t)t * B_ * V_, pval, pidx);
    }
}